// Round 1
// baseline (1277.509 us; speedup 1.0000x reference)
//
#include <hip/hip_runtime.h>

#define BATCH 4
#define NPTS 4096
#define KNBR 16
#define D 64
#define NQ (BATCH * NPTS)

__device__ __forceinline__ float rl(float v, int i) {
  return __int_as_float(__builtin_amdgcn_readlane(__float_as_int(v), i));
}

// ---------------------------------------------------------------------------
// Kernel 1: exact KNN (top-16 by (dist asc, idx asc)), bit-exact fp32 dists.
// 128 threads = 64 queries x 2 scan-chunks. Coords staged in LDS (48KB).
// ---------------------------------------------------------------------------
__global__ __launch_bounds__(128) void knn_kernel(const float* __restrict__ coords,
                                                  int* __restrict__ knn) {
  __shared__ float cx[NPTS], cy[NPTS], cz[NPTS];
  __shared__ unsigned long long mbuf[64][2][16];
  const int b = blockIdx.x >> 6;
  const int qblk = blockIdx.x & 63;
  const int t = threadIdx.x;
  const float* cb = coords + (size_t)b * NPTS * 3;
  for (int e = t; e < NPTS * 3; e += 128) {
    float v = cb[e];
    int n = e / 3, d = e - n * 3;
    if (d == 0) cx[n] = v; else if (d == 1) cy[n] = v; else cz[n] = v;
  }
  __syncthreads();
  const int ql = t >> 1, sub = t & 1;
  const int qi = qblk * 64 + ql;
  const float qx = cx[qi], qy = cy[qi], qz = cz[qi];
  unsigned long long best[16];
#pragma unroll
  for (int i = 0; i < 16; ++i) best[i] = 0x7F800000FFFFFFFFull;  // (+inf, maxidx)
  float worst = __int_as_float(0x7f800000);
  for (int s = 0; s < NPTS / 2; ++s) {
    const int j = (s << 1) | sub;
    float dx = __fsub_rn(qx, cx[j]);
    float dy = __fsub_rn(qy, cy[j]);
    float dz = __fsub_rn(qz, cz[j]);
    float d = __fadd_rn(__fadd_rn(__fmul_rn(dx, dx), __fmul_rn(dy, dy)), __fmul_rn(dz, dz));
    if (d < worst) {
      unsigned long long key = ((unsigned long long)__float_as_uint(d) << 32) | (unsigned)j;
#pragma unroll
      for (int i = 0; i < 16; ++i) {
        unsigned long long bi = best[i];
        bool c = key < bi;
        unsigned long long nb = c ? key : bi;
        key = c ? bi : key;
        best[i] = nb;
      }
      worst = __uint_as_float((unsigned)(best[15] >> 32));
    }
  }
#pragma unroll
  for (int i = 0; i < 16; ++i) mbuf[ql][sub][i] = best[i];
  __syncthreads();
  if (sub == 0) {
    int h0 = 0, h1 = 0;
    const int gq = b * NPTS + qi;
    for (int m = 0; m < 16; ++m) {
      unsigned long long k0 = mbuf[ql][0][h0];
      unsigned long long k1 = mbuf[ql][1][h1];
      if (k0 < k1) { knn[gq * 16 + m] = (int)(k0 & 0xFFFFFFFFu); ++h0; }
      else         { knn[gq * 16 + m] = (int)(k1 & 0xFFFFFFFFu); ++h1; }
    }
  }
}

// ---------------------------------------------------------------------------
// Kernel 2: x = feat@w1+b1; q=x@wq; k=x@wk; v=x@wv.  Wave-per-row, lane=channel,
// cross-channel broadcast via v_readlane. Weights in LDS (64KB).
// ---------------------------------------------------------------------------
#define FT_RPT 8
__global__ __launch_bounds__(256) void ft_kernel(const float* __restrict__ feat,
    const float* __restrict__ w1, const float* __restrict__ b1,
    const float* __restrict__ wq, const float* __restrict__ wk, const float* __restrict__ wv,
    float* __restrict__ qo, float* __restrict__ ko, float* __restrict__ vo) {
  __shared__ float W[4][D * D];
  const int t = threadIdx.x;
  {
    const float4* s0 = (const float4*)w1;
    const float4* s1 = (const float4*)wq;
    const float4* s2 = (const float4*)wk;
    const float4* s3 = (const float4*)wv;
    float4* d0 = (float4*)W[0];
    float4* d1 = (float4*)W[1];
    float4* d2 = (float4*)W[2];
    float4* d3 = (float4*)W[3];
    for (int c = t; c < D * D / 4; c += 256) {
      d0[c] = s0[c]; d1[c] = s1[c]; d2[c] = s2[c]; d3[c] = s3[c];
    }
  }
  __syncthreads();
  const int f = t & 63, w = t >> 6;
  const float b1f = b1[f];
  const int gw = blockIdx.x * 4 + w;
  for (int r = 0; r < FT_RPT; ++r) {
    const int row = gw * FT_RPT + r;
    const float fv = feat[(size_t)row * D + f];
    float x = b1f;
#pragma unroll
    for (int i = 0; i < D; ++i) x = fmaf(rl(fv, i), W[0][i * D + f], x);
    float q = 0.f, kk = 0.f, vv = 0.f;
#pragma unroll
    for (int i = 0; i < D; ++i) {
      float xi = rl(x, i);
      q  = fmaf(xi, W[1][i * D + f], q);
      kk = fmaf(xi, W[2][i * D + f], kk);
      vv = fmaf(xi, W[3][i * D + f], vv);
    }
    qo[(size_t)row * D + f] = q;
    ko[(size_t)row * D + f] = kk;
    vo[(size_t)row * D + f] = vv;
  }
}

// ---------------------------------------------------------------------------
// Kernel 3: pos-enc MLP, attention MLP, softmax over K, output.
// Wave-per-query, lane=channel. WP2/WM1/WM2 in LDS (48KB) + per-wave PE
// buffer (16KB). w2 read from global (used once per query, L2-hot).
// Raw attn scores staged in their final d_out slot, then overwritten.
// ---------------------------------------------------------------------------
#define MK_RPT 2
__global__ __launch_bounds__(256) void pt_kernel(const float* __restrict__ coords,
    const float* __restrict__ feat,
    const float* __restrict__ qws, const float* __restrict__ kws, const float* __restrict__ vws,
    const int* __restrict__ knn,
    const float* __restrict__ wp1, const float* __restrict__ bp1,
    const float* __restrict__ wp2, const float* __restrict__ bp2,
    const float* __restrict__ wm1, const float* __restrict__ bm1,
    const float* __restrict__ wm2, const float* __restrict__ bm2,
    const float* __restrict__ w2g, const float* __restrict__ b2,
    float* __restrict__ out, float* __restrict__ attn) {
  __shared__ float WP2[D * D], WM1[D * D], WM2[D * D];
  __shared__ float PE[4][KNBR * D];
  const int t = threadIdx.x;
  for (int c = t; c < D * D / 4; c += 256) {
    ((float4*)WP2)[c] = ((const float4*)wp2)[c];
    ((float4*)WM1)[c] = ((const float4*)wm1)[c];
    ((float4*)WM2)[c] = ((const float4*)wm2)[c];
  }
  __syncthreads();
  const int f = t & 63, w = t >> 6;
  const float wp10 = wp1[f], wp11 = wp1[D + f], wp12 = wp1[2 * D + f];
  const float bp1f = bp1[f], bp2f = bp2[f];
  const float bm1f = bm1[f], bm2f = bm2[f], b2f = b2[f];
  float* pe = PE[w];
  const int gw = blockIdx.x * 4 + w;
  for (int r = 0; r < MK_RPT; ++r) {
    const int qi = gw * MK_RPT + r;
    const int base = qi & ~(NPTS - 1);
    const float qf = qws[(size_t)qi * D + f];
    const float cqx = coords[(size_t)qi * 3];
    const float cqy = coords[(size_t)qi * 3 + 1];
    const float cqz = coords[(size_t)qi * 3 + 2];
    const int* kn = knn + (size_t)qi * KNBR;
    float* attq = attn + (size_t)qi * KNBR * D;
    for (int k = 0; k < KNBR; ++k) {
      const int gj = base + kn[k];
      const float rx = cqx - coords[(size_t)gj * 3];
      const float ry = cqy - coords[(size_t)gj * 3 + 1];
      const float rz = cqz - coords[(size_t)gj * 3 + 2];
      float h1 = fmaf(rx, wp10, fmaf(ry, wp11, fmaf(rz, wp12, bp1f)));
      h1 = fmaxf(h1, 0.f);
      float acc = bp2f;
#pragma unroll
      for (int i = 0; i < D; ++i) acc = fmaf(rl(h1, i), WP2[i * D + f], acc);
      pe[k * D + f] = acc;                       // pos_enc, reused at output
      const float a = qf - kws[(size_t)gj * D + f] + acc;
      float a2 = bm1f;
#pragma unroll
      for (int i = 0; i < D; ++i) a2 = fmaf(rl(a, i), WM1[i * D + f], a2);
      a2 = fmaxf(a2, 0.f);
      float a3 = bm2f;
#pragma unroll
      for (int i = 0; i < D; ++i) a3 = fmaf(rl(a2, i), WM2[i * D + f], a3);
      attq[k * D + f] = a3;                      // raw score, overwritten below
    }
    // softmax over K (per lane/channel), then output accumulation
    float tv[KNBR];
#pragma unroll
    for (int k = 0; k < KNBR; ++k) tv[k] = attq[k * D + f] * 0.125f;
    float m = tv[0];
#pragma unroll
    for (int k = 1; k < KNBR; ++k) m = fmaxf(m, tv[k]);
    float s = 0.f, e[KNBR];
#pragma unroll
    for (int k = 0; k < KNBR; ++k) { e[k] = expf(tv[k] - m); s += e[k]; }
    const float rs = 1.0f / s;
    float ov = 0.f;
#pragma unroll
    for (int k = 0; k < KNBR; ++k) {
      const float at = e[k] * rs;
      attq[k * D + f] = at;                      // final attn output
      const int gj = base + kn[k];
      ov = fmaf(at, vws[(size_t)gj * D + f] + pe[k * D + f], ov);
    }
    float o2 = b2f;
#pragma unroll
    for (int i = 0; i < D; ++i) o2 = fmaf(rl(ov, i), w2g[i * D + f], o2);
    out[(size_t)qi * D + f] = o2 + feat[(size_t)qi * D + f];
  }
}

// ---------------------------------------------------------------------------
extern "C" void kernel_launch(void* const* d_in, const int* in_sizes, int n_in,
                              void* d_out, int out_size, void* d_ws, size_t ws_size,
                              hipStream_t stream) {
  const float* coords = (const float*)d_in[0];
  const float* feat   = (const float*)d_in[1];
  const float* w1  = (const float*)d_in[2];
  const float* b1  = (const float*)d_in[3];
  const float* w2  = (const float*)d_in[4];
  const float* b2  = (const float*)d_in[5];
  const float* wq  = (const float*)d_in[6];
  const float* wk  = (const float*)d_in[7];
  const float* wv  = (const float*)d_in[8];
  const float* wm1 = (const float*)d_in[9];
  const float* bm1 = (const float*)d_in[10];
  const float* wm2 = (const float*)d_in[11];
  const float* bm2 = (const float*)d_in[12];
  const float* wp1 = (const float*)d_in[13];
  const float* bp1 = (const float*)d_in[14];
  const float* wp2 = (const float*)d_in[15];
  const float* bp2 = (const float*)d_in[16];

  int*   knn = (int*)d_ws;
  float* qws = (float*)((char*)d_ws + (size_t)(1 << 20));
  float* kws = (float*)((char*)d_ws + (size_t)5 * (1 << 20));
  float* vws = (float*)((char*)d_ws + (size_t)9 * (1 << 20));
  float* out  = (float*)d_out;
  float* attn = out + (size_t)NQ * D;

  hipLaunchKernelGGL(knn_kernel, dim3(BATCH * (NPTS / 64)), dim3(128), 0, stream,
                     coords, knn);
  hipLaunchKernelGGL(ft_kernel, dim3(NQ / (4 * FT_RPT)), dim3(256), 0, stream,
                     feat, w1, b1, wq, wk, wv, qws, kws, vws);
  hipLaunchKernelGGL(pt_kernel, dim3(NQ / (4 * MK_RPT)), dim3(256), 0, stream,
                     coords, feat, qws, kws, vws, knn,
                     wp1, bp1, wp2, bp2, wm1, bm1, wm2, bm2, w2, b2, out, attn);
}

// Round 3
// 475.308 us; speedup vs baseline: 2.6878x; 2.6878x over previous
//
#include <hip/hip_runtime.h>
#include <hip/hip_bf16.h>

#define BATCH 4
#define NPTS 4096
#define KNBR 16
#define D 64
#define NQ (BATCH * NPTS)

using short8 = __attribute__((ext_vector_type(8))) short;
using f32x4 = __attribute__((ext_vector_type(4))) float;

__device__ __forceinline__ float rl(float v, int i) {
  return __int_as_float(__builtin_amdgcn_readlane(__float_as_int(v), i));
}
__device__ __forceinline__ short f2bf(float x) {
  __hip_bfloat16 h = __float2bfloat16(x);
  return *reinterpret_cast<short*>(&h);
}
__device__ __forceinline__ float bf2f(short s) {
  union { unsigned u; float f; } v;
  v.u = ((unsigned)(unsigned short)s) << 16;
  return v.f;
}
#define MFMA16(a, b, c) __builtin_amdgcn_mfma_f32_16x16x32_bf16(a, b, c, 0, 0, 0)

// ---------------------------------------------------------------------------
// Kernel 1: fused exact KNN (top-16 by (dist asc, idx asc)), bit-exact fp32.
// Grid = B * 256 blocks; 256 thr = 16 queries x 16 subs. Candidates staged in
// LDS in 4 chunks of 1024. Each sub scans 256 candidates total with a u64-key
// ((dist_bits<<32)|idx) insertion network; two-stage in-block 16-way merge.
// No global scratch beyond the final knn indices -> no d_ws aliasing.
// ---------------------------------------------------------------------------
__global__ __launch_bounds__(256) void knn_kernel(const float* __restrict__ coords,
                                                  int* __restrict__ knn) {
  __shared__ float cx[1024], cy[1024], cz[1024];
  __shared__ unsigned long long mbuf[16][16][16];
  __shared__ unsigned long long mbuf2[16][4][16];
  const int b = blockIdx.x >> 8;
  const int blk = blockIdx.x & 255;
  const int t = threadIdx.x;
  const int q = t >> 4, sub = t & 15;
  const int qi = blk * 16 + q;  // local query index within batch
  const float* cb = coords + (size_t)b * NPTS * 3;
  const float qx = cb[(size_t)qi * 3];
  const float qy = cb[(size_t)qi * 3 + 1];
  const float qz = cb[(size_t)qi * 3 + 2];
  unsigned long long best[16];
#pragma unroll
  for (int i = 0; i < 16; ++i) best[i] = 0x7F800000FFFFFFFFull;
  unsigned long long wk = 0x7F800000FFFFFFFFull;
  for (int c = 0; c < 4; ++c) {
    __syncthreads();  // previous chunk fully consumed before restage
    for (int e = t; e < 3072; e += 256) {
      float v = cb[(size_t)(c * 1024) * 3 + e];
      int n = e / 3, d = e - n * 3;
      if (d == 0) cx[n] = v; else if (d == 1) cy[n] = v; else cz[n] = v;
    }
    __syncthreads();
    const int jbase = sub * 64;
    for (int s = 0; s < 64; ++s) {
      const int jl = jbase + s;
      float dx = __fsub_rn(qx, cx[jl]);
      float dy = __fsub_rn(qy, cy[jl]);
      float dz = __fsub_rn(qz, cz[jl]);
      float d = __fadd_rn(__fadd_rn(__fmul_rn(dx, dx), __fmul_rn(dy, dy)), __fmul_rn(dz, dz));
      unsigned long long key = ((unsigned long long)__float_as_uint(d) << 32) | (unsigned)(c * 1024 + jl);
      if (key < wk) {
#pragma unroll
        for (int i = 0; i < 16; ++i) {
          unsigned long long bi = best[i];
          bool cc = key < bi;
          unsigned long long nb = cc ? key : bi;
          key = cc ? bi : key;
          best[i] = nb;
        }
        wk = best[15];
      }
    }
  }
#pragma unroll
  for (int i = 0; i < 16; ++i) mbuf[q][sub][i] = best[i];
  __syncthreads();
  if (t < 64) {  // stage A: 4 threads/query, each merges 4 sorted 16-lists
    const int q2 = t >> 2, quad = t & 3;
    const unsigned long long* l0 = mbuf[q2][quad * 4 + 0];
    const unsigned long long* l1 = mbuf[q2][quad * 4 + 1];
    const unsigned long long* l2 = mbuf[q2][quad * 4 + 2];
    const unsigned long long* l3 = mbuf[q2][quad * 4 + 3];
    unsigned long long* dst = mbuf2[q2][quad];
    int p0 = 0, p1 = 0, p2 = 0, p3 = 0;
    for (int m = 0; m < 16; ++m) {
      unsigned long long k0 = l0[p0];
      unsigned long long k1 = l1[p1];
      unsigned long long k2 = l2[p2];
      unsigned long long k3 = l3[p3];
      bool a01 = k0 <= k1; unsigned long long m01 = a01 ? k0 : k1;
      bool a23 = k2 <= k3; unsigned long long m23 = a23 ? k2 : k3;
      bool af = m01 <= m23; unsigned long long mm = af ? m01 : m23;
      p0 += (af && a01); p1 += (af && !a01); p2 += (!af && a23); p3 += (!af && !a23);
      dst[m] = mm;
    }
  }
  __syncthreads();
  if (t < 16) {  // stage B: final 4-way merge -> global knn
    const unsigned long long* l0 = mbuf2[t][0];
    const unsigned long long* l1 = mbuf2[t][1];
    const unsigned long long* l2 = mbuf2[t][2];
    const unsigned long long* l3 = mbuf2[t][3];
    int* dst = knn + ((size_t)b * NPTS + blk * 16 + t) * 16;
    int p0 = 0, p1 = 0, p2 = 0, p3 = 0;
    for (int m = 0; m < 16; ++m) {
      unsigned long long k0 = l0[p0];
      unsigned long long k1 = l1[p1];
      unsigned long long k2 = l2[p2];
      unsigned long long k3 = l3[p3];
      bool a01 = k0 <= k1; unsigned long long m01 = a01 ? k0 : k1;
      bool a23 = k2 <= k3; unsigned long long m23 = a23 ? k2 : k3;
      bool af = m01 <= m23; unsigned long long mm = af ? m01 : m23;
      p0 += (af && a01); p1 += (af && !a01); p2 += (!af && a23); p3 += (!af && !a23);
      dst[m] = (int)(mm & 0xFFFFFFFFu);
    }
  }
}

// ---------------------------------------------------------------------------
// Kernel 2: x = feat@w1+b1; q=x@wq; k=x@wk; v=x@wv (wave-per-row, readlane).
// ---------------------------------------------------------------------------
#define FT_RPT 8
__global__ __launch_bounds__(256) void ft_kernel(const float* __restrict__ feat,
    const float* __restrict__ w1, const float* __restrict__ b1,
    const float* __restrict__ wq, const float* __restrict__ wk, const float* __restrict__ wv,
    float* __restrict__ qo, float* __restrict__ ko, float* __restrict__ vo) {
  __shared__ float W[4][D * D];
  const int t = threadIdx.x;
  {
    const float4* s0 = (const float4*)w1;
    const float4* s1 = (const float4*)wq;
    const float4* s2 = (const float4*)wk;
    const float4* s3 = (const float4*)wv;
    for (int c = t; c < D * D / 4; c += 256) {
      ((float4*)W[0])[c] = s0[c]; ((float4*)W[1])[c] = s1[c];
      ((float4*)W[2])[c] = s2[c]; ((float4*)W[3])[c] = s3[c];
    }
  }
  __syncthreads();
  const int f = t & 63, w = t >> 6;
  const float b1f = b1[f];
  const int gw = blockIdx.x * 4 + w;
  for (int r = 0; r < FT_RPT; ++r) {
    const int row = gw * FT_RPT + r;
    const float fv = feat[(size_t)row * D + f];
    float x = b1f;
#pragma unroll
    for (int i = 0; i < D; ++i) x = fmaf(rl(fv, i), W[0][i * D + f], x);
    float q = 0.f, kk = 0.f, vv = 0.f;
#pragma unroll
    for (int i = 0; i < D; ++i) {
      float xi = rl(x, i);
      q  = fmaf(xi, W[1][i * D + f], q);
      kk = fmaf(xi, W[2][i * D + f], kk);
      vv = fmaf(xi, W[3][i * D + f], vv);
    }
    qo[(size_t)row * D + f] = q;
    ko[(size_t)row * D + f] = kk;
    vo[(size_t)row * D + f] = vv;
  }
}

// ---------------------------------------------------------------------------
// Kernel 3: MFMA point-transformer core. Wave per query.
// A-frag: lane l holds A[l&15][8*(l>>4)+j+32*ks]  (neighbor x channel)
// B-frag: lane l holds B[8*(l>>4)+j+32*ks][(l&15)+16*t] (pre-packed in LDS)
// D-frag: lane l reg r holds D[4*(l>>4)+r][(l&15)+16*t]
// Explicit __syncthreads() between every LDS write phase and its readers.
// ---------------------------------------------------------------------------
__global__ __launch_bounds__(256) void pt_kernel(const float* __restrict__ coords,
    const float* __restrict__ feat,
    const float* __restrict__ qws, const float* __restrict__ kws, const float* __restrict__ vws,
    const int* __restrict__ knn,
    const float* __restrict__ wp1, const float* __restrict__ bp1,
    const float* __restrict__ wp2, const float* __restrict__ bp2,
    const float* __restrict__ wm1, const float* __restrict__ bm1,
    const float* __restrict__ wm2, const float* __restrict__ bm2,
    const float* __restrict__ w2, const float* __restrict__ b2,
    float* __restrict__ out, float* __restrict__ attn_g) {
  __shared__ short WBp[512 * 8], WBm1[512 * 8], WBm2[512 * 8];  // frag-packed weights
  __shared__ short w2b[D * D];
  __shared__ float wp1t[D * 4];       // (wp1_x, wp1_y, wp1_z, bp1) per channel
  __shared__ float biases[4 * D];     // bp2, bm1, bm2, b2
  __shared__ int knnq[4][16];
  __shared__ float pe_s[4][16][68];   // per-wave pos_enc (f32), padded
  __shared__ short a_s[4][16][72];    // per-wave bf16 activation roundtrip, padded

  const int t = threadIdx.x;
  // ---- weight prep (frag order: dst[((t*2+ks)*64 + lane)*8 + j] = W[k][n]) ----
  for (int s = t; s < 512 * 3; s += 256) {
    const int m = s >> 9, rem = s & 511;
    const int tk = rem >> 6, l = rem & 63;
    const int tt = tk >> 1, ks = tk & 1;
    const float* src = (m == 0) ? wp2 : ((m == 1) ? wm1 : wm2);
    short* dst = (m == 0) ? WBp : ((m == 1) ? WBm1 : WBm2);
#pragma unroll
    for (int j = 0; j < 8; ++j) {
      const int k = ((l >> 4) << 3) + j + (ks << 5);
      const int n = (l & 15) + (tt << 4);
      dst[rem * 8 + j] = f2bf(src[k * D + n]);
    }
  }
  for (int s = t; s < D * D; s += 256) w2b[s] = f2bf(w2[s]);
  if (t < 64) {
    wp1t[t * 4 + 0] = wp1[t];
    wp1t[t * 4 + 1] = wp1[D + t];
    wp1t[t * 4 + 2] = wp1[2 * D + t];
    wp1t[t * 4 + 3] = bp1[t];
    biases[t] = bp2[t]; biases[64 + t] = bm1[t];
    biases[128 + t] = bm2[t]; biases[192 + t] = b2[t];
  }
  const int w = t >> 6, lane = t & 63;
  const int qi = blockIdx.x * 4 + w;
  const int bbase = (qi >> 12) << 12;
  if (lane < 16) knnq[w][lane] = bbase + knn[(size_t)qi * 16 + lane];
  __syncthreads();

  const int l15 = lane & 15, g = lane >> 4;
  // ---- h1 = relu(rel @ wp1 + bp1), built directly in A-frag layout ----
  const int gjA = knnq[w][l15];
  const float qx = coords[(size_t)qi * 3], qy = coords[(size_t)qi * 3 + 1], qz = coords[(size_t)qi * 3 + 2];
  const float rx = qx - coords[(size_t)gjA * 3];
  const float ry = qy - coords[(size_t)gjA * 3 + 1];
  const float rz = qz - coords[(size_t)gjA * 3 + 2];
  short8 ha[2];
#pragma unroll
  for (int ks = 0; ks < 2; ++ks) {
#pragma unroll
    for (int j = 0; j < 8; ++j) {
      const int c = g * 8 + j + ks * 32;
      const float4 wv = *(const float4*)&wp1t[c * 4];
      float h = fmaf(rx, wv.x, fmaf(ry, wv.y, fmaf(rz, wv.z, wv.w)));
      ha[ks][j] = f2bf(fmaxf(h, 0.f));
    }
  }
  // ---- pos_enc = h1 @ wp2 + bp2 ----
  f32x4 pe_d[4];
#pragma unroll
  for (int tt = 0; tt < 4; ++tt) {
    f32x4 acc = {0.f, 0.f, 0.f, 0.f};
    acc = MFMA16(ha[0], *(const short8*)&WBp[((tt * 2 + 0) * 64 + lane) * 8], acc);
    acc = MFMA16(ha[1], *(const short8*)&WBp[((tt * 2 + 1) * 64 + lane) * 8], acc);
    const float bb = biases[l15 + tt * 16];
#pragma unroll
    for (int r = 0; r < 4; ++r) pe_d[tt][r] = acc[r] + bb;
  }
#pragma unroll
  for (int tt = 0; tt < 4; ++tt)
#pragma unroll
    for (int r = 0; r < 4; ++r) pe_s[w][4 * g + r][l15 + 16 * tt] = pe_d[tt][r];
  __syncthreads();  // pe_s visible to all lanes before cross-lane reads
  // ---- a = q - k_g + pos_enc, in A-frag layout ----
  short8 aa[2];
#pragma unroll
  for (int ks = 0; ks < 2; ++ks) {
    const int c0 = g * 8 + ks * 32;
    const float4 q0 = *(const float4*)&qws[(size_t)qi * D + c0];
    const float4 q1 = *(const float4*)&qws[(size_t)qi * D + c0 + 4];
    const float4 k0 = *(const float4*)&kws[(size_t)gjA * D + c0];
    const float4 k1 = *(const float4*)&kws[(size_t)gjA * D + c0 + 4];
    const float4 p0 = *(const float4*)&pe_s[w][l15][c0];
    const float4 p1 = *(const float4*)&pe_s[w][l15][c0 + 4];
    aa[ks][0] = f2bf(q0.x - k0.x + p0.x);
    aa[ks][1] = f2bf(q0.y - k0.y + p0.y);
    aa[ks][2] = f2bf(q0.z - k0.z + p0.z);
    aa[ks][3] = f2bf(q0.w - k0.w + p0.w);
    aa[ks][4] = f2bf(q1.x - k1.x + p1.x);
    aa[ks][5] = f2bf(q1.y - k1.y + p1.y);
    aa[ks][6] = f2bf(q1.z - k1.z + p1.z);
    aa[ks][7] = f2bf(q1.w - k1.w + p1.w);
  }
  // ---- a2 = relu(a @ wm1 + bm1) -> bf16 -> LDS roundtrip ----
#pragma unroll
  for (int tt = 0; tt < 4; ++tt) {
    f32x4 acc = {0.f, 0.f, 0.f, 0.f};
    acc = MFMA16(aa[0], *(const short8*)&WBm1[((tt * 2 + 0) * 64 + lane) * 8], acc);
    acc = MFMA16(aa[1], *(const short8*)&WBm1[((tt * 2 + 1) * 64 + lane) * 8], acc);
    const float bb = biases[64 + l15 + tt * 16];
#pragma unroll
    for (int r = 0; r < 4; ++r)
      a_s[w][4 * g + r][l15 + 16 * tt] = f2bf(fmaxf(acc[r] + bb, 0.f));
  }
  __syncthreads();  // a_s visible before cross-lane reads
  // ---- a3 = a2 @ wm2 + bm2 ----
  const short8 a20 = *(const short8*)&a_s[w][l15][g * 8];
  const short8 a21 = *(const short8*)&a_s[w][l15][g * 8 + 32];
  f32x4 s3[4];
#pragma unroll
  for (int tt = 0; tt < 4; ++tt) {
    f32x4 acc = {0.f, 0.f, 0.f, 0.f};
    acc = MFMA16(a20, *(const short8*)&WBm2[((tt * 2 + 0) * 64 + lane) * 8], acc);
    acc = MFMA16(a21, *(const short8*)&WBm2[((tt * 2 + 1) * 64 + lane) * 8], acc);
    const float bb = biases[128 + l15 + tt * 16];
#pragma unroll
    for (int r = 0; r < 4; ++r) s3[tt][r] = acc[r] + bb;
  }
  // ---- softmax over the 16 neighbors (rows), per channel (col) ----
  float att[4][4];
#pragma unroll
  for (int tt = 0; tt < 4; ++tt) {
    float v0 = s3[tt][0] * 0.125f, v1 = s3[tt][1] * 0.125f;
    float v2 = s3[tt][2] * 0.125f, v3 = s3[tt][3] * 0.125f;
    float mx = fmaxf(fmaxf(v0, v1), fmaxf(v2, v3));
    mx = fmaxf(mx, __shfl_xor(mx, 16));
    mx = fmaxf(mx, __shfl_xor(mx, 32));
    float e0 = __expf(v0 - mx), e1 = __expf(v1 - mx), e2 = __expf(v2 - mx), e3 = __expf(v3 - mx);
    float sm = (e0 + e1) + (e2 + e3);
    sm += __shfl_xor(sm, 16);
    sm += __shfl_xor(sm, 32);
    const float inv = 1.0f / sm;
    att[tt][0] = e0 * inv; att[tt][1] = e1 * inv;
    att[tt][2] = e2 * inv; att[tt][3] = e3 * inv;
  }
  // ---- store attn output ----
  float* aq = attn_g + (size_t)qi * KNBR * D;
#pragma unroll
  for (int tt = 0; tt < 4; ++tt)
#pragma unroll
    for (int r = 0; r < 4; ++r)
      aq[(4 * g + r) * D + l15 + 16 * tt] = att[tt][r];
  // ---- out_vec = sum_k attn * (v_g + pos_enc) ----
  float ovp[4] = {0.f, 0.f, 0.f, 0.f};
#pragma unroll
  for (int r = 0; r < 4; ++r) {
    const int gjr = knnq[w][4 * g + r];
#pragma unroll
    for (int tt = 0; tt < 4; ++tt) {
      const float vv = vws[(size_t)gjr * D + l15 + 16 * tt];
      const float pp = pe_s[w][4 * g + r][l15 + 16 * tt];
      ovp[tt] = fmaf(att[tt][r], vv + pp, ovp[tt]);
    }
  }
#pragma unroll
  for (int tt = 0; tt < 4; ++tt) {
    ovp[tt] += __shfl_xor(ovp[tt], 16);
    ovp[tt] += __shfl_xor(ovp[tt], 32);
  }
  float ov = (g == 0) ? ovp[0] : ((g == 1) ? ovp[1] : ((g == 2) ? ovp[2] : ovp[3]));
  // ---- out = ov @ w2 + b2 + feat ----
  float o2 = biases[192 + lane];
#pragma unroll
  for (int i = 0; i < D; ++i)
    o2 = fmaf(rl(ov, i), bf2f(w2b[i * D + lane]), o2);
  out[(size_t)qi * D + lane] = o2 + feat[(size_t)qi * D + lane];
}

// ---------------------------------------------------------------------------
extern "C" void kernel_launch(void* const* d_in, const int* in_sizes, int n_in,
                              void* d_out, int out_size, void* d_ws, size_t ws_size,
                              hipStream_t stream) {
  const float* coords = (const float*)d_in[0];
  const float* feat   = (const float*)d_in[1];
  const float* w1  = (const float*)d_in[2];
  const float* b1  = (const float*)d_in[3];
  const float* w2  = (const float*)d_in[4];
  const float* b2  = (const float*)d_in[5];
  const float* wq  = (const float*)d_in[6];
  const float* wk  = (const float*)d_in[7];
  const float* wv  = (const float*)d_in[8];
  const float* wm1 = (const float*)d_in[9];
  const float* bm1 = (const float*)d_in[10];
  const float* wm2 = (const float*)d_in[11];
  const float* bm2 = (const float*)d_in[12];
  const float* wp1 = (const float*)d_in[13];
  const float* bp1 = (const float*)d_in[14];
  const float* wp2 = (const float*)d_in[15];
  const float* bp2 = (const float*)d_in[16];

  // ws layout (disjoint, round-1-proven footprint): knn@0 (1MB),
  // qws@1MB, kws@5MB, vws@9MB..13MB.
  int* knn = (int*)d_ws;
  float* qws = (float*)((char*)d_ws + (size_t)1 * (1 << 20));
  float* kws = (float*)((char*)d_ws + (size_t)5 * (1 << 20));
  float* vws = (float*)((char*)d_ws + (size_t)9 * (1 << 20));
  float* out  = (float*)d_out;
  float* attn = out + (size_t)NQ * D;

  hipLaunchKernelGGL(knn_kernel, dim3(BATCH * 256), dim3(256), 0, stream,
                     coords, knn);
  hipLaunchKernelGGL(ft_kernel, dim3(NQ / (4 * FT_RPT)), dim3(256), 0, stream,
                     feat, w1, b1, wq, wk, wv, qws, kws, vws);
  hipLaunchKernelGGL(pt_kernel, dim3(NQ / 4), dim3(256), 0, stream,
                     coords, feat, qws, kws, vws, knn,
                     wp1, bp1, wp2, bp2, wm1, bm1, wm2, bm2, w2, b2, out, attn);
}

// Round 4
// 179.892 us; speedup vs baseline: 7.1015x; 2.6422x over previous
//
#include <hip/hip_runtime.h>
#include <hip/hip_bf16.h>

#define BATCH 4
#define NPTS 4096
#define KNBR 16
#define D 64
#define NQ (BATCH * NPTS)

using short8 = __attribute__((ext_vector_type(8))) short;
using f32x4 = __attribute__((ext_vector_type(4))) float;

__device__ __forceinline__ float rl(float v, int i) {
  return __int_as_float(__builtin_amdgcn_readlane(__float_as_int(v), i));
}
__device__ __forceinline__ short f2bf(float x) {
  __hip_bfloat16 h = __float2bfloat16(x);
  return *reinterpret_cast<short*>(&h);
}
__device__ __forceinline__ float bf2f(short s) {
  union { unsigned u; float f; } v;
  v.u = ((unsigned)(unsigned short)s) << 16;
  return v.f;
}
#define MFMA16(a, b, c) __builtin_amdgcn_mfma_f32_16x16x32_bf16(a, b, c, 0, 0, 0)

#define INF_KEY 0x7F800000FFFFFFFFull

// 64-lane bitonic full sort (ascending by lane) of u64 keys.
__device__ __forceinline__ unsigned long long bitonic64(unsigned long long v, int lane) {
#pragma unroll
  for (int k = 2; k <= 64; k <<= 1) {
#pragma unroll
    for (int j = k >> 1; j > 0; j >>= 1) {
      unsigned long long o = __shfl_xor(v, j);
      const bool up = (lane & k) == 0;
      const bool lower = (lane & j) == 0;
      unsigned long long mn = v < o ? v : o;
      unsigned long long mx = v < o ? o : v;
      v = (up == lower) ? mn : mx;
    }
  }
  return v;
}

// ---------------------------------------------------------------------------
// Kernel 1: exact KNN, wave-per-query. Slice-min threshold + filter + bitonic.
// Phase 1: lane l takes branchless u64-key min over slice {c*1024+s*64+l}
//   (LDS candidate reads are lane-consecutive -> conflict-free).
// The 64 slice minima are 64 distinct points; the 16th-smallest key K16 thus
// satisfies count(key <= K16) >= 16, so the true top-16 all have key <= K16.
// Phase 2: rescan, append keys <= K16 to per-wave buffer (E[count] ~ 19).
// Phase 3: bitonic sort (inf-padded) -> lanes 0..15 write exact sorted top-16.
// ---------------------------------------------------------------------------
__global__ __launch_bounds__(256, 8) void knn_kernel(const float* __restrict__ coords,
                                                     int* __restrict__ knn) {
  __shared__ float cx[1024], cy[1024], cz[1024];
  __shared__ unsigned long long buf[4][64];
  __shared__ int cnt[4];
  const int t = threadIdx.x;
  const int w = t >> 6, lane = t & 63;
  const int qg = blockIdx.x * 4 + w;
  const int b = qg >> 12;
  const int qi = qg & (NPTS - 1);
  const float* cb = coords + (size_t)b * NPTS * 3;
  const float qx = cb[(size_t)qi * 3];
  const float qy = cb[(size_t)qi * 3 + 1];
  const float qz = cb[(size_t)qi * 3 + 2];

  // ---- phase 1: per-lane slice minimum ----
  unsigned long long m = INF_KEY;
  for (int c = 0; c < 4; ++c) {
    __syncthreads();
    for (int e = t; e < 3072; e += 256) {
      float v = cb[(size_t)(c * 1024) * 3 + e];
      int n = e / 3, d = e - n * 3;
      if (d == 0) cx[n] = v; else if (d == 1) cy[n] = v; else cz[n] = v;
    }
    __syncthreads();
#pragma unroll 4
    for (int s = 0; s < 16; ++s) {
      const int jl = s * 64 + lane;
      float dx = __fsub_rn(qx, cx[jl]);
      float dy = __fsub_rn(qy, cy[jl]);
      float dz = __fsub_rn(qz, cz[jl]);
      float d = __fadd_rn(__fadd_rn(__fmul_rn(dx, dx), __fmul_rn(dy, dy)), __fmul_rn(dz, dz));
      unsigned long long key = ((unsigned long long)__float_as_uint(d) << 32) | (unsigned)(c * 1024 + jl);
      m = key < m ? key : m;
    }
  }
  // ---- threshold: 16th-smallest slice-min key ----
  unsigned long long K16 = __shfl(bitonic64(m, lane), 15);

  // ---- phase 2: filter-append ----
  if (lane == 0) cnt[w] = 0;
  for (int c = 0; c < 4; ++c) {
    __syncthreads();
    for (int e = t; e < 3072; e += 256) {
      float v = cb[(size_t)(c * 1024) * 3 + e];
      int n = e / 3, d = e - n * 3;
      if (d == 0) cx[n] = v; else if (d == 1) cy[n] = v; else cz[n] = v;
    }
    __syncthreads();
#pragma unroll 4
    for (int s = 0; s < 16; ++s) {
      const int jl = s * 64 + lane;
      float dx = __fsub_rn(qx, cx[jl]);
      float dy = __fsub_rn(qy, cy[jl]);
      float dz = __fsub_rn(qz, cz[jl]);
      float d = __fadd_rn(__fadd_rn(__fmul_rn(dx, dx), __fmul_rn(dy, dy)), __fmul_rn(dz, dz));
      unsigned long long key = ((unsigned long long)__float_as_uint(d) << 32) | (unsigned)(c * 1024 + jl);
      if (key <= K16) {
        int slot = atomicAdd(&cnt[w], 1);
        if (slot < 64) buf[w][slot] = key;
      }
    }
  }
  // ---- phase 3: exact sort of the filtered set ----
  const int n = cnt[w];                 // per-wave LDS ops are in program order
  unsigned long long v = (lane < n) ? buf[w][lane] : INF_KEY;
  v = bitonic64(v, lane);
  if (lane < 16) knn[(size_t)qg * 16 + lane] = (int)(v & 0xFFFFFFFFu);
}

// ---------------------------------------------------------------------------
// Kernel 2: x = feat@w1+b1; q=x@wq; k=x@wk; v=x@wv (wave-per-row, readlane).
// ---------------------------------------------------------------------------
#define FT_RPT 8
__global__ __launch_bounds__(256) void ft_kernel(const float* __restrict__ feat,
    const float* __restrict__ w1, const float* __restrict__ b1,
    const float* __restrict__ wq, const float* __restrict__ wk, const float* __restrict__ wv,
    float* __restrict__ qo, float* __restrict__ ko, float* __restrict__ vo) {
  __shared__ float W[4][D * D];
  const int t = threadIdx.x;
  {
    const float4* s0 = (const float4*)w1;
    const float4* s1 = (const float4*)wq;
    const float4* s2 = (const float4*)wk;
    const float4* s3 = (const float4*)wv;
    for (int c = t; c < D * D / 4; c += 256) {
      ((float4*)W[0])[c] = s0[c]; ((float4*)W[1])[c] = s1[c];
      ((float4*)W[2])[c] = s2[c]; ((float4*)W[3])[c] = s3[c];
    }
  }
  __syncthreads();
  const int f = t & 63, w = t >> 6;
  const float b1f = b1[f];
  const int gw = blockIdx.x * 4 + w;
  for (int r = 0; r < FT_RPT; ++r) {
    const int row = gw * FT_RPT + r;
    const float fv = feat[(size_t)row * D + f];
    float x = b1f;
#pragma unroll
    for (int i = 0; i < D; ++i) x = fmaf(rl(fv, i), W[0][i * D + f], x);
    float q = 0.f, kk = 0.f, vv = 0.f;
#pragma unroll
    for (int i = 0; i < D; ++i) {
      float xi = rl(x, i);
      q  = fmaf(xi, W[1][i * D + f], q);
      kk = fmaf(xi, W[2][i * D + f], kk);
      vv = fmaf(xi, W[3][i * D + f], vv);
    }
    qo[(size_t)row * D + f] = q;
    ko[(size_t)row * D + f] = kk;
    vo[(size_t)row * D + f] = vv;
  }
}

// ---------------------------------------------------------------------------
// Kernel 3: MFMA point-transformer core. Wave per query.
// A-frag: lane l holds A[l&15][8*(l>>4)+j+32*ks]  (neighbor x channel)
// B-frag: lane l holds B[8*(l>>4)+j+32*ks][(l&15)+16*t] (pre-packed in LDS)
// D-frag: lane l reg r holds D[4*(l>>4)+r][(l&15)+16*t]
// Explicit __syncthreads() between every LDS write phase and its readers.
// ---------------------------------------------------------------------------
__global__ __launch_bounds__(256) void pt_kernel(const float* __restrict__ coords,
    const float* __restrict__ feat,
    const float* __restrict__ qws, const float* __restrict__ kws, const float* __restrict__ vws,
    const int* __restrict__ knn,
    const float* __restrict__ wp1, const float* __restrict__ bp1,
    const float* __restrict__ wp2, const float* __restrict__ bp2,
    const float* __restrict__ wm1, const float* __restrict__ bm1,
    const float* __restrict__ wm2, const float* __restrict__ bm2,
    const float* __restrict__ w2, const float* __restrict__ b2,
    float* __restrict__ out, float* __restrict__ attn_g) {
  __shared__ short WBp[512 * 8], WBm1[512 * 8], WBm2[512 * 8];  // frag-packed weights
  __shared__ short w2b[D * D];
  __shared__ float wp1t[D * 4];       // (wp1_x, wp1_y, wp1_z, bp1) per channel
  __shared__ float biases[4 * D];     // bp2, bm1, bm2, b2
  __shared__ int knnq[4][16];
  __shared__ float pe_s[4][16][68];   // per-wave pos_enc (f32), padded
  __shared__ short a_s[4][16][72];    // per-wave bf16 activation roundtrip, padded

  const int t = threadIdx.x;
  // ---- weight prep (frag order: dst[((t*2+ks)*64 + lane)*8 + j] = W[k][n]) ----
  for (int s = t; s < 512 * 3; s += 256) {
    const int m = s >> 9, rem = s & 511;
    const int tk = rem >> 6, l = rem & 63;
    const int tt = tk >> 1, ks = tk & 1;
    const float* src = (m == 0) ? wp2 : ((m == 1) ? wm1 : wm2);
    short* dst = (m == 0) ? WBp : ((m == 1) ? WBm1 : WBm2);
#pragma unroll
    for (int j = 0; j < 8; ++j) {
      const int k = ((l >> 4) << 3) + j + (ks << 5);
      const int n = (l & 15) + (tt << 4);
      dst[rem * 8 + j] = f2bf(src[k * D + n]);
    }
  }
  for (int s = t; s < D * D; s += 256) w2b[s] = f2bf(w2[s]);
  if (t < 64) {
    wp1t[t * 4 + 0] = wp1[t];
    wp1t[t * 4 + 1] = wp1[D + t];
    wp1t[t * 4 + 2] = wp1[2 * D + t];
    wp1t[t * 4 + 3] = bp1[t];
    biases[t] = bp2[t]; biases[64 + t] = bm1[t];
    biases[128 + t] = bm2[t]; biases[192 + t] = b2[t];
  }
  const int w = t >> 6, lane = t & 63;
  const int qi = blockIdx.x * 4 + w;
  const int bbase = (qi >> 12) << 12;
  if (lane < 16) knnq[w][lane] = bbase + knn[(size_t)qi * 16 + lane];
  __syncthreads();

  const int l15 = lane & 15, g = lane >> 4;
  // ---- h1 = relu(rel @ wp1 + bp1), built directly in A-frag layout ----
  const int gjA = knnq[w][l15];
  const float qx = coords[(size_t)qi * 3], qy = coords[(size_t)qi * 3 + 1], qz = coords[(size_t)qi * 3 + 2];
  const float rx = qx - coords[(size_t)gjA * 3];
  const float ry = qy - coords[(size_t)gjA * 3 + 1];
  const float rz = qz - coords[(size_t)gjA * 3 + 2];
  short8 ha[2];
#pragma unroll
  for (int ks = 0; ks < 2; ++ks) {
#pragma unroll
    for (int j = 0; j < 8; ++j) {
      const int c = g * 8 + j + ks * 32;
      const float4 wv = *(const float4*)&wp1t[c * 4];
      float h = fmaf(rx, wv.x, fmaf(ry, wv.y, fmaf(rz, wv.z, wv.w)));
      ha[ks][j] = f2bf(fmaxf(h, 0.f));
    }
  }
  // ---- pos_enc = h1 @ wp2 + bp2 ----
  f32x4 pe_d[4];
#pragma unroll
  for (int tt = 0; tt < 4; ++tt) {
    f32x4 acc = {0.f, 0.f, 0.f, 0.f};
    acc = MFMA16(ha[0], *(const short8*)&WBp[((tt * 2 + 0) * 64 + lane) * 8], acc);
    acc = MFMA16(ha[1], *(const short8*)&WBp[((tt * 2 + 1) * 64 + lane) * 8], acc);
    const float bb = biases[l15 + tt * 16];
#pragma unroll
    for (int r = 0; r < 4; ++r) pe_d[tt][r] = acc[r] + bb;
  }
#pragma unroll
  for (int tt = 0; tt < 4; ++tt)
#pragma unroll
    for (int r = 0; r < 4; ++r) pe_s[w][4 * g + r][l15 + 16 * tt] = pe_d[tt][r];
  __syncthreads();  // pe_s visible to all lanes before cross-lane reads
  // ---- a = q - k_g + pos_enc, in A-frag layout ----
  short8 aa[2];
#pragma unroll
  for (int ks = 0; ks < 2; ++ks) {
    const int c0 = g * 8 + ks * 32;
    const float4 q0 = *(const float4*)&qws[(size_t)qi * D + c0];
    const float4 q1 = *(const float4*)&qws[(size_t)qi * D + c0 + 4];
    const float4 k0 = *(const float4*)&kws[(size_t)gjA * D + c0];
    const float4 k1 = *(const float4*)&kws[(size_t)gjA * D + c0 + 4];
    const float4 p0 = *(const float4*)&pe_s[w][l15][c0];
    const float4 p1 = *(const float4*)&pe_s[w][l15][c0 + 4];
    aa[ks][0] = f2bf(q0.x - k0.x + p0.x);
    aa[ks][1] = f2bf(q0.y - k0.y + p0.y);
    aa[ks][2] = f2bf(q0.z - k0.z + p0.z);
    aa[ks][3] = f2bf(q0.w - k0.w + p0.w);
    aa[ks][4] = f2bf(q1.x - k1.x + p1.x);
    aa[ks][5] = f2bf(q1.y - k1.y + p1.y);
    aa[ks][6] = f2bf(q1.z - k1.z + p1.z);
    aa[ks][7] = f2bf(q1.w - k1.w + p1.w);
  }
  // ---- a2 = relu(a @ wm1 + bm1) -> bf16 -> LDS roundtrip ----
#pragma unroll
  for (int tt = 0; tt < 4; ++tt) {
    f32x4 acc = {0.f, 0.f, 0.f, 0.f};
    acc = MFMA16(aa[0], *(const short8*)&WBm1[((tt * 2 + 0) * 64 + lane) * 8], acc);
    acc = MFMA16(aa[1], *(const short8*)&WBm1[((tt * 2 + 1) * 64 + lane) * 8], acc);
    const float bb = biases[64 + l15 + tt * 16];
#pragma unroll
    for (int r = 0; r < 4; ++r)
      a_s[w][4 * g + r][l15 + 16 * tt] = f2bf(fmaxf(acc[r] + bb, 0.f));
  }
  __syncthreads();  // a_s visible before cross-lane reads
  // ---- a3 = a2 @ wm2 + bm2 ----
  const short8 a20 = *(const short8*)&a_s[w][l15][g * 8];
  const short8 a21 = *(const short8*)&a_s[w][l15][g * 8 + 32];
  f32x4 s3[4];
#pragma unroll
  for (int tt = 0; tt < 4; ++tt) {
    f32x4 acc = {0.f, 0.f, 0.f, 0.f};
    acc = MFMA16(a20, *(const short8*)&WBm2[((tt * 2 + 0) * 64 + lane) * 8], acc);
    acc = MFMA16(a21, *(const short8*)&WBm2[((tt * 2 + 1) * 64 + lane) * 8], acc);
    const float bb = biases[128 + l15 + tt * 16];
#pragma unroll
    for (int r = 0; r < 4; ++r) s3[tt][r] = acc[r] + bb;
  }
  // ---- softmax over the 16 neighbors (rows), per channel (col) ----
  float att[4][4];
#pragma unroll
  for (int tt = 0; tt < 4; ++tt) {
    float v0 = s3[tt][0] * 0.125f, v1 = s3[tt][1] * 0.125f;
    float v2 = s3[tt][2] * 0.125f, v3 = s3[tt][3] * 0.125f;
    float mx = fmaxf(fmaxf(v0, v1), fmaxf(v2, v3));
    mx = fmaxf(mx, __shfl_xor(mx, 16));
    mx = fmaxf(mx, __shfl_xor(mx, 32));
    float e0 = __expf(v0 - mx), e1 = __expf(v1 - mx), e2 = __expf(v2 - mx), e3 = __expf(v3 - mx);
    float sm = (e0 + e1) + (e2 + e3);
    sm += __shfl_xor(sm, 16);
    sm += __shfl_xor(sm, 32);
    const float inv = 1.0f / sm;
    att[tt][0] = e0 * inv; att[tt][1] = e1 * inv;
    att[tt][2] = e2 * inv; att[tt][3] = e3 * inv;
  }
  // ---- store attn output ----
  float* aq = attn_g + (size_t)qi * KNBR * D;
#pragma unroll
  for (int tt = 0; tt < 4; ++tt)
#pragma unroll
    for (int r = 0; r < 4; ++r)
      aq[(4 * g + r) * D + l15 + 16 * tt] = att[tt][r];
  // ---- out_vec = sum_k attn * (v_g + pos_enc) ----
  float ovp[4] = {0.f, 0.f, 0.f, 0.f};
#pragma unroll
  for (int r = 0; r < 4; ++r) {
    const int gjr = knnq[w][4 * g + r];
#pragma unroll
    for (int tt = 0; tt < 4; ++tt) {
      const float vv = vws[(size_t)gjr * D + l15 + 16 * tt];
      const float pp = pe_s[w][4 * g + r][l15 + 16 * tt];
      ovp[tt] = fmaf(att[tt][r], vv + pp, ovp[tt]);
    }
  }
#pragma unroll
  for (int tt = 0; tt < 4; ++tt) {
    ovp[tt] += __shfl_xor(ovp[tt], 16);
    ovp[tt] += __shfl_xor(ovp[tt], 32);
  }
  float ov = (g == 0) ? ovp[0] : ((g == 1) ? ovp[1] : ((g == 2) ? ovp[2] : ovp[3]));
  // ---- out = ov @ w2 + b2 + feat ----
  float o2 = biases[192 + lane];
#pragma unroll
  for (int i = 0; i < D; ++i)
    o2 = fmaf(rl(ov, i), bf2f(w2b[i * D + lane]), o2);
  out[(size_t)qi * D + lane] = o2 + feat[(size_t)qi * D + lane];
}

// ---------------------------------------------------------------------------
extern "C" void kernel_launch(void* const* d_in, const int* in_sizes, int n_in,
                              void* d_out, int out_size, void* d_ws, size_t ws_size,
                              hipStream_t stream) {
  const float* coords = (const float*)d_in[0];
  const float* feat   = (const float*)d_in[1];
  const float* w1  = (const float*)d_in[2];
  const float* b1  = (const float*)d_in[3];
  const float* w2  = (const float*)d_in[4];
  const float* b2  = (const float*)d_in[5];
  const float* wq  = (const float*)d_in[6];
  const float* wk  = (const float*)d_in[7];
  const float* wv  = (const float*)d_in[8];
  const float* wm1 = (const float*)d_in[9];
  const float* bm1 = (const float*)d_in[10];
  const float* wm2 = (const float*)d_in[11];
  const float* bm2 = (const float*)d_in[12];
  const float* wp1 = (const float*)d_in[13];
  const float* bp1 = (const float*)d_in[14];
  const float* wp2 = (const float*)d_in[15];
  const float* bp2 = (const float*)d_in[16];

  // ws layout (disjoint): knn@0 (1MB), qws@1MB, kws@5MB, vws@9MB..13MB.
  int* knn = (int*)d_ws;
  float* qws = (float*)((char*)d_ws + (size_t)1 * (1 << 20));
  float* kws = (float*)((char*)d_ws + (size_t)5 * (1 << 20));
  float* vws = (float*)((char*)d_ws + (size_t)9 * (1 << 20));
  float* out  = (float*)d_out;
  float* attn = out + (size_t)NQ * D;

  hipLaunchKernelGGL(knn_kernel, dim3(NQ / 4), dim3(256), 0, stream,
                     coords, knn);
  hipLaunchKernelGGL(ft_kernel, dim3(NQ / (4 * FT_RPT)), dim3(256), 0, stream,
                     feat, w1, b1, wq, wk, wv, qws, kws, vws);
  hipLaunchKernelGGL(pt_kernel, dim3(NQ / 4), dim3(256), 0, stream,
                     coords, feat, qws, kws, vws, knn,
                     wp1, bp1, wp2, bp2, wm1, bm1, wm2, bm2, w2, b2, out, attn);
}

// Round 5
// 151.551 us; speedup vs baseline: 8.4295x; 1.1870x over previous
//
#include <hip/hip_runtime.h>
#include <hip/hip_bf16.h>

#define BATCH 4
#define NPTS 4096
#define KNBR 16
#define D 64
#define NQ (BATCH * NPTS)
#define QPW 4

using short8 = __attribute__((ext_vector_type(8))) short;
using f32x4 = __attribute__((ext_vector_type(4))) float;

__device__ __forceinline__ float rl(float v, int i) {
  return __int_as_float(__builtin_amdgcn_readlane(__float_as_int(v), i));
}
__device__ __forceinline__ short f2bf(float x) {
  __hip_bfloat16 h = __float2bfloat16(x);
  return *reinterpret_cast<short*>(&h);
}
__device__ __forceinline__ float bf2f(short s) {
  union { unsigned u; float f; } v;
  v.u = ((unsigned)(unsigned short)s) << 16;
  return v.f;
}
#define MFMA16(a, b, c) __builtin_amdgcn_mfma_f32_16x16x32_bf16(a, b, c, 0, 0, 0)

#define INF_KEY 0x7F800000FFFFFFFFull

// 64-lane bitonic full sort (ascending by lane) of u64 keys.
__device__ __forceinline__ unsigned long long bitonic64(unsigned long long v, int lane) {
#pragma unroll
  for (int k = 2; k <= 64; k <<= 1) {
#pragma unroll
    for (int j = k >> 1; j > 0; j >>= 1) {
      unsigned long long o = __shfl_xor(v, j);
      const bool up = (lane & k) == 0;
      const bool lower = (lane & j) == 0;
      unsigned long long mn = v < o ? v : o;
      unsigned long long mx = v < o ? o : v;
      v = (up == lower) ? mn : mx;
    }
  }
  return v;
}

// ---------------------------------------------------------------------------
// Kernel 1: exact KNN. 4 queries per wave (16/block). Two-pass slice-min
// threshold + filter + bitonic, with the candidate LDS reads and staging
// amortized across the wave's 4 queries. Per-query threshold semantics are
// identical to the proven round-4 kernel (same slice partition -> same K16).
// Staging is a branch-free float4 copy into interleaved cs[3072]; candidate
// reads cs[3*jl] hit bank 3l%32 -> 2 lanes/bank (conflict-free).
// ---------------------------------------------------------------------------
__global__ __launch_bounds__(256, 8) void knn_kernel(const float* __restrict__ coords,
                                                     int* __restrict__ knn) {
  __shared__ float cs[3072];                       // 1024 pts, xyz interleaved
  __shared__ unsigned long long buf[4][QPW][64];   // filter buffers
  __shared__ int cnt[4][QPW];
  const int t = threadIdx.x;
  const int w = t >> 6, lane = t & 63;
  const int qbase = blockIdx.x * (4 * QPW) + w * QPW;   // first query of this wave
  const int b = qbase >> 12;
  const float* cb = coords + (size_t)b * NPTS * 3;

  float qx[QPW], qy[QPW], qz[QPW];
  unsigned long long m[QPW];
#pragma unroll
  for (int q = 0; q < QPW; ++q) {
    const int qi = (qbase + q) & (NPTS - 1);
    qx[q] = cb[(size_t)qi * 3];
    qy[q] = cb[(size_t)qi * 3 + 1];
    qz[q] = cb[(size_t)qi * 3 + 2];
    m[q] = INF_KEY;
  }

  // ---- phase 1: per-lane slice minima (4 queries at once) ----
  for (int c = 0; c < 4; ++c) {
    __syncthreads();
    const float4* src = (const float4*)(cb + (size_t)c * 3072);
#pragma unroll
    for (int i = 0; i < 3; ++i) ((float4*)cs)[t + i * 256] = src[t + i * 256];
    __syncthreads();
#pragma unroll 4
    for (int s = 0; s < 16; ++s) {
      const int jl = s * 64 + lane;
      const float px = cs[3 * jl], py = cs[3 * jl + 1], pz = cs[3 * jl + 2];
      const unsigned idx = (unsigned)(c * 1024 + jl);
#pragma unroll
      for (int q = 0; q < QPW; ++q) {
        float dx = __fsub_rn(qx[q], px);
        float dy = __fsub_rn(qy[q], py);
        float dz = __fsub_rn(qz[q], pz);
        float d = __fadd_rn(__fadd_rn(__fmul_rn(dx, dx), __fmul_rn(dy, dy)), __fmul_rn(dz, dz));
        unsigned long long key = ((unsigned long long)__float_as_uint(d) << 32) | idx;
        m[q] = key < m[q] ? key : m[q];
      }
    }
  }
  // ---- thresholds: 16th-smallest slice-min key per query ----
  unsigned long long K16[QPW];
#pragma unroll
  for (int q = 0; q < QPW; ++q) K16[q] = __shfl(bitonic64(m[q], lane), 15);
  if (lane < QPW) cnt[w][lane] = 0;

  // ---- phase 2: filter-append ----
  for (int c = 0; c < 4; ++c) {
    __syncthreads();
    const float4* src = (const float4*)(cb + (size_t)c * 3072);
#pragma unroll
    for (int i = 0; i < 3; ++i) ((float4*)cs)[t + i * 256] = src[t + i * 256];
    __syncthreads();
#pragma unroll 4
    for (int s = 0; s < 16; ++s) {
      const int jl = s * 64 + lane;
      const float px = cs[3 * jl], py = cs[3 * jl + 1], pz = cs[3 * jl + 2];
      const unsigned idx = (unsigned)(c * 1024 + jl);
#pragma unroll
      for (int q = 0; q < QPW; ++q) {
        float dx = __fsub_rn(qx[q], px);
        float dy = __fsub_rn(qy[q], py);
        float dz = __fsub_rn(qz[q], pz);
        float d = __fadd_rn(__fadd_rn(__fmul_rn(dx, dx), __fmul_rn(dy, dy)), __fmul_rn(dz, dz));
        unsigned long long key = ((unsigned long long)__float_as_uint(d) << 32) | idx;
        if (key <= K16[q]) {
          int slot = atomicAdd(&cnt[w][q], 1);
          if (slot < 64) buf[w][q][slot] = key;
        }
      }
    }
  }
  // ---- phase 3: exact sort of each filtered set ----
#pragma unroll
  for (int q = 0; q < QPW; ++q) {
    const int n = cnt[w][q];
    unsigned long long v = (lane < n) ? buf[w][q][lane] : INF_KEY;
    v = bitonic64(v, lane);
    if (lane < 16) knn[(size_t)(qbase + q) * 16 + lane] = (int)(v & 0xFFFFFFFFu);
  }
}

// ---------------------------------------------------------------------------
// Kernel 2: x = feat@w1+b1; q=x@wq; k=x@wk; v=x@wv (wave-per-row, readlane).
// ---------------------------------------------------------------------------
#define FT_RPT 8
__global__ __launch_bounds__(256) void ft_kernel(const float* __restrict__ feat,
    const float* __restrict__ w1, const float* __restrict__ b1,
    const float* __restrict__ wq, const float* __restrict__ wk, const float* __restrict__ wv,
    float* __restrict__ qo, float* __restrict__ ko, float* __restrict__ vo) {
  __shared__ float W[4][D * D];
  const int t = threadIdx.x;
  {
    const float4* s0 = (const float4*)w1;
    const float4* s1 = (const float4*)wq;
    const float4* s2 = (const float4*)wk;
    const float4* s3 = (const float4*)wv;
    for (int c = t; c < D * D / 4; c += 256) {
      ((float4*)W[0])[c] = s0[c]; ((float4*)W[1])[c] = s1[c];
      ((float4*)W[2])[c] = s2[c]; ((float4*)W[3])[c] = s3[c];
    }
  }
  __syncthreads();
  const int f = t & 63, w = t >> 6;
  const float b1f = b1[f];
  const int gw = blockIdx.x * 4 + w;
  for (int r = 0; r < FT_RPT; ++r) {
    const int row = gw * FT_RPT + r;
    const float fv = feat[(size_t)row * D + f];
    float x = b1f;
#pragma unroll
    for (int i = 0; i < D; ++i) x = fmaf(rl(fv, i), W[0][i * D + f], x);
    float q = 0.f, kk = 0.f, vv = 0.f;
#pragma unroll
    for (int i = 0; i < D; ++i) {
      float xi = rl(x, i);
      q  = fmaf(xi, W[1][i * D + f], q);
      kk = fmaf(xi, W[2][i * D + f], kk);
      vv = fmaf(xi, W[3][i * D + f], vv);
    }
    qo[(size_t)row * D + f] = q;
    ko[(size_t)row * D + f] = kk;
    vo[(size_t)row * D + f] = vv;
  }
}

// ---------------------------------------------------------------------------
// Kernel 3: MFMA point-transformer core. Wave per query.
// A-frag: lane l holds A[l&15][8*(l>>4)+j+32*ks]  (neighbor x channel)
// B-frag: lane l holds B[8*(l>>4)+j+32*ks][(l&15)+16*t] (pre-packed in LDS)
// D-frag: lane l reg r holds D[4*(l>>4)+r][(l&15)+16*t]
// Explicit __syncthreads() between every LDS write phase and its readers.
// ---------------------------------------------------------------------------
__global__ __launch_bounds__(256) void pt_kernel(const float* __restrict__ coords,
    const float* __restrict__ feat,
    const float* __restrict__ qws, const float* __restrict__ kws, const float* __restrict__ vws,
    const int* __restrict__ knn,
    const float* __restrict__ wp1, const float* __restrict__ bp1,
    const float* __restrict__ wp2, const float* __restrict__ bp2,
    const float* __restrict__ wm1, const float* __restrict__ bm1,
    const float* __restrict__ wm2, const float* __restrict__ bm2,
    const float* __restrict__ w2, const float* __restrict__ b2,
    float* __restrict__ out, float* __restrict__ attn_g) {
  __shared__ short WBp[512 * 8], WBm1[512 * 8], WBm2[512 * 8];  // frag-packed weights
  __shared__ short w2b[D * D];
  __shared__ float wp1t[D * 4];       // (wp1_x, wp1_y, wp1_z, bp1) per channel
  __shared__ float biases[4 * D];     // bp2, bm1, bm2, b2
  __shared__ int knnq[4][16];
  __shared__ float pe_s[4][16][68];   // per-wave pos_enc (f32), padded
  __shared__ short a_s[4][16][72];    // per-wave bf16 activation roundtrip, padded

  const int t = threadIdx.x;
  // ---- weight prep (frag order: dst[((t*2+ks)*64 + lane)*8 + j] = W[k][n]) ----
  for (int s = t; s < 512 * 3; s += 256) {
    const int m = s >> 9, rem = s & 511;
    const int tk = rem >> 6, l = rem & 63;
    const int tt = tk >> 1, ks = tk & 1;
    const float* src = (m == 0) ? wp2 : ((m == 1) ? wm1 : wm2);
    short* dst = (m == 0) ? WBp : ((m == 1) ? WBm1 : WBm2);
#pragma unroll
    for (int j = 0; j < 8; ++j) {
      const int k = ((l >> 4) << 3) + j + (ks << 5);
      const int n = (l & 15) + (tt << 4);
      dst[rem * 8 + j] = f2bf(src[k * D + n]);
    }
  }
  for (int s = t; s < D * D; s += 256) w2b[s] = f2bf(w2[s]);
  if (t < 64) {
    wp1t[t * 4 + 0] = wp1[t];
    wp1t[t * 4 + 1] = wp1[D + t];
    wp1t[t * 4 + 2] = wp1[2 * D + t];
    wp1t[t * 4 + 3] = bp1[t];
    biases[t] = bp2[t]; biases[64 + t] = bm1[t];
    biases[128 + t] = bm2[t]; biases[192 + t] = b2[t];
  }
  const int w = t >> 6, lane = t & 63;
  const int qi = blockIdx.x * 4 + w;
  const int bbase = (qi >> 12) << 12;
  if (lane < 16) knnq[w][lane] = bbase + knn[(size_t)qi * 16 + lane];
  __syncthreads();

  const int l15 = lane & 15, g = lane >> 4;
  // ---- h1 = relu(rel @ wp1 + bp1), built directly in A-frag layout ----
  const int gjA = knnq[w][l15];
  const float qx = coords[(size_t)qi * 3], qy = coords[(size_t)qi * 3 + 1], qz = coords[(size_t)qi * 3 + 2];
  const float rx = qx - coords[(size_t)gjA * 3];
  const float ry = qy - coords[(size_t)gjA * 3 + 1];
  const float rz = qz - coords[(size_t)gjA * 3 + 2];
  short8 ha[2];
#pragma unroll
  for (int ks = 0; ks < 2; ++ks) {
#pragma unroll
    for (int j = 0; j < 8; ++j) {
      const int c = g * 8 + j + ks * 32;
      const float4 wv = *(const float4*)&wp1t[c * 4];
      float h = fmaf(rx, wv.x, fmaf(ry, wv.y, fmaf(rz, wv.z, wv.w)));
      ha[ks][j] = f2bf(fmaxf(h, 0.f));
    }
  }
  // ---- pos_enc = h1 @ wp2 + bp2 ----
  f32x4 pe_d[4];
#pragma unroll
  for (int tt = 0; tt < 4; ++tt) {
    f32x4 acc = {0.f, 0.f, 0.f, 0.f};
    acc = MFMA16(ha[0], *(const short8*)&WBp[((tt * 2 + 0) * 64 + lane) * 8], acc);
    acc = MFMA16(ha[1], *(const short8*)&WBp[((tt * 2 + 1) * 64 + lane) * 8], acc);
    const float bb = biases[l15 + tt * 16];
#pragma unroll
    for (int r = 0; r < 4; ++r) pe_d[tt][r] = acc[r] + bb;
  }
#pragma unroll
  for (int tt = 0; tt < 4; ++tt)
#pragma unroll
    for (int r = 0; r < 4; ++r) pe_s[w][4 * g + r][l15 + 16 * tt] = pe_d[tt][r];
  __syncthreads();  // pe_s visible to all lanes before cross-lane reads
  // ---- a = q - k_g + pos_enc, in A-frag layout ----
  short8 aa[2];
#pragma unroll
  for (int ks = 0; ks < 2; ++ks) {
    const int c0 = g * 8 + ks * 32;
    const float4 q0 = *(const float4*)&qws[(size_t)qi * D + c0];
    const float4 q1 = *(const float4*)&qws[(size_t)qi * D + c0 + 4];
    const float4 k0 = *(const float4*)&kws[(size_t)gjA * D + c0];
    const float4 k1 = *(const float4*)&kws[(size_t)gjA * D + c0 + 4];
    const float4 p0 = *(const float4*)&pe_s[w][l15][c0];
    const float4 p1 = *(const float4*)&pe_s[w][l15][c0 + 4];
    aa[ks][0] = f2bf(q0.x - k0.x + p0.x);
    aa[ks][1] = f2bf(q0.y - k0.y + p0.y);
    aa[ks][2] = f2bf(q0.z - k0.z + p0.z);
    aa[ks][3] = f2bf(q0.w - k0.w + p0.w);
    aa[ks][4] = f2bf(q1.x - k1.x + p1.x);
    aa[ks][5] = f2bf(q1.y - k1.y + p1.y);
    aa[ks][6] = f2bf(q1.z - k1.z + p1.z);
    aa[ks][7] = f2bf(q1.w - k1.w + p1.w);
  }
  // ---- a2 = relu(a @ wm1 + bm1) -> bf16 -> LDS roundtrip ----
#pragma unroll
  for (int tt = 0; tt < 4; ++tt) {
    f32x4 acc = {0.f, 0.f, 0.f, 0.f};
    acc = MFMA16(aa[0], *(const short8*)&WBm1[((tt * 2 + 0) * 64 + lane) * 8], acc);
    acc = MFMA16(aa[1], *(const short8*)&WBm1[((tt * 2 + 1) * 64 + lane) * 8], acc);
    const float bb = biases[64 + l15 + tt * 16];
#pragma unroll
    for (int r = 0; r < 4; ++r)
      a_s[w][4 * g + r][l15 + 16 * tt] = f2bf(fmaxf(acc[r] + bb, 0.f));
  }
  __syncthreads();  // a_s visible before cross-lane reads
  // ---- a3 = a2 @ wm2 + bm2 ----
  const short8 a20 = *(const short8*)&a_s[w][l15][g * 8];
  const short8 a21 = *(const short8*)&a_s[w][l15][g * 8 + 32];
  f32x4 s3[4];
#pragma unroll
  for (int tt = 0; tt < 4; ++tt) {
    f32x4 acc = {0.f, 0.f, 0.f, 0.f};
    acc = MFMA16(a20, *(const short8*)&WBm2[((tt * 2 + 0) * 64 + lane) * 8], acc);
    acc = MFMA16(a21, *(const short8*)&WBm2[((tt * 2 + 1) * 64 + lane) * 8], acc);
    const float bb = biases[128 + l15 + tt * 16];
#pragma unroll
    for (int r = 0; r < 4; ++r) s3[tt][r] = acc[r] + bb;
  }
  // ---- softmax over the 16 neighbors (rows), per channel (col) ----
  float att[4][4];
#pragma unroll
  for (int tt = 0; tt < 4; ++tt) {
    float v0 = s3[tt][0] * 0.125f, v1 = s3[tt][1] * 0.125f;
    float v2 = s3[tt][2] * 0.125f, v3 = s3[tt][3] * 0.125f;
    float mx = fmaxf(fmaxf(v0, v1), fmaxf(v2, v3));
    mx = fmaxf(mx, __shfl_xor(mx, 16));
    mx = fmaxf(mx, __shfl_xor(mx, 32));
    float e0 = __expf(v0 - mx), e1 = __expf(v1 - mx), e2 = __expf(v2 - mx), e3 = __expf(v3 - mx);
    float sm = (e0 + e1) + (e2 + e3);
    sm += __shfl_xor(sm, 16);
    sm += __shfl_xor(sm, 32);
    const float inv = 1.0f / sm;
    att[tt][0] = e0 * inv; att[tt][1] = e1 * inv;
    att[tt][2] = e2 * inv; att[tt][3] = e3 * inv;
  }
  // ---- store attn output ----
  float* aq = attn_g + (size_t)qi * KNBR * D;
#pragma unroll
  for (int tt = 0; tt < 4; ++tt)
#pragma unroll
    for (int r = 0; r < 4; ++r)
      aq[(4 * g + r) * D + l15 + 16 * tt] = att[tt][r];
  // ---- out_vec = sum_k attn * (v_g + pos_enc) ----
  float ovp[4] = {0.f, 0.f, 0.f, 0.f};
#pragma unroll
  for (int r = 0; r < 4; ++r) {
    const int gjr = knnq[w][4 * g + r];
#pragma unroll
    for (int tt = 0; tt < 4; ++tt) {
      const float vv = vws[(size_t)gjr * D + l15 + 16 * tt];
      const float pp = pe_s[w][4 * g + r][l15 + 16 * tt];
      ovp[tt] = fmaf(att[tt][r], vv + pp, ovp[tt]);
    }
  }
#pragma unroll
  for (int tt = 0; tt < 4; ++tt) {
    ovp[tt] += __shfl_xor(ovp[tt], 16);
    ovp[tt] += __shfl_xor(ovp[tt], 32);
  }
  float ov = (g == 0) ? ovp[0] : ((g == 1) ? ovp[1] : ((g == 2) ? ovp[2] : ovp[3]));
  // ---- out = ov @ w2 + b2 + feat ----
  float o2 = biases[192 + lane];
#pragma unroll
  for (int i = 0; i < D; ++i)
    o2 = fmaf(rl(ov, i), bf2f(w2b[i * D + lane]), o2);
  out[(size_t)qi * D + lane] = o2 + feat[(size_t)qi * D + lane];
}

// ---------------------------------------------------------------------------
extern "C" void kernel_launch(void* const* d_in, const int* in_sizes, int n_in,
                              void* d_out, int out_size, void* d_ws, size_t ws_size,
                              hipStream_t stream) {
  const float* coords = (const float*)d_in[0];
  const float* feat   = (const float*)d_in[1];
  const float* w1  = (const float*)d_in[2];
  const float* b1  = (const float*)d_in[3];
  const float* w2  = (const float*)d_in[4];
  const float* b2  = (const float*)d_in[5];
  const float* wq  = (const float*)d_in[6];
  const float* wk  = (const float*)d_in[7];
  const float* wv  = (const float*)d_in[8];
  const float* wm1 = (const float*)d_in[9];
  const float* bm1 = (const float*)d_in[10];
  const float* wm2 = (const float*)d_in[11];
  const float* bm2 = (const float*)d_in[12];
  const float* wp1 = (const float*)d_in[13];
  const float* bp1 = (const float*)d_in[14];
  const float* wp2 = (const float*)d_in[15];
  const float* bp2 = (const float*)d_in[16];

  // ws layout (disjoint): knn@0 (1MB), qws@1MB, kws@5MB, vws@9MB..13MB.
  int* knn = (int*)d_ws;
  float* qws = (float*)((char*)d_ws + (size_t)1 * (1 << 20));
  float* kws = (float*)((char*)d_ws + (size_t)5 * (1 << 20));
  float* vws = (float*)((char*)d_ws + (size_t)9 * (1 << 20));
  float* out  = (float*)d_out;
  float* attn = out + (size_t)NQ * D;

  hipLaunchKernelGGL(knn_kernel, dim3(NQ / (4 * QPW)), dim3(256), 0, stream,
                     coords, knn);
  hipLaunchKernelGGL(ft_kernel, dim3(NQ / (4 * FT_RPT)), dim3(256), 0, stream,
                     feat, w1, b1, wq, wk, wv, qws, kws, vws);
  hipLaunchKernelGGL(pt_kernel, dim3(NQ / 4), dim3(256), 0, stream,
                     coords, feat, qws, kws, vws, knn,
                     wp1, bp1, wp2, bp2, wm1, bm1, wm2, bm2, w2, b2, out, attn);
}

// Round 6
// 137.301 us; speedup vs baseline: 9.3044x; 1.1038x over previous
//
#include <hip/hip_runtime.h>
#include <hip/hip_bf16.h>

#define BATCH 4
#define NPTS 4096
#define KNBR 16
#define D 64
#define NQ (BATCH * NPTS)
#define QPW 4
#define PT_QPW 4

using short8 = __attribute__((ext_vector_type(8))) short;
using f32x4 = __attribute__((ext_vector_type(4))) float;

__device__ __forceinline__ float rl(float v, int i) {
  return __int_as_float(__builtin_amdgcn_readlane(__float_as_int(v), i));
}
__device__ __forceinline__ short f2bf(float x) {
  __hip_bfloat16 h = __float2bfloat16(x);
  return *reinterpret_cast<short*>(&h);
}
__device__ __forceinline__ float bf2f(short s) {
  union { unsigned u; float f; } v;
  v.u = ((unsigned)(unsigned short)s) << 16;
  return v.f;
}
#define MFMA16(a, b, c) __builtin_amdgcn_mfma_f32_16x16x32_bf16(a, b, c, 0, 0, 0)

#define INF_KEY 0x7F800000FFFFFFFFull

// 64-lane bitonic full sort (ascending by lane) of u64 keys.
__device__ __forceinline__ unsigned long long bitonic64(unsigned long long v, int lane) {
#pragma unroll
  for (int k = 2; k <= 64; k <<= 1) {
#pragma unroll
    for (int j = k >> 1; j > 0; j >>= 1) {
      unsigned long long o = __shfl_xor(v, j);
      const bool up = (lane & k) == 0;
      const bool lower = (lane & j) == 0;
      unsigned long long mn = v < o ? v : o;
      unsigned long long mx = v < o ? o : v;
      v = (up == lower) ? mn : mx;
    }
  }
  return v;
}

// ---------------------------------------------------------------------------
// Kernel 1: exact KNN, 4 queries/wave, candidates read directly from global
// (coords stream is L2-resident: 48KB/batch). No staging, no barriers.
// Same slice partition (j = s*64+lane) and __f*_rn arithmetic as the proven
// round-4/5 kernel -> identical keys, identical K16 threshold semantics.
// ---------------------------------------------------------------------------
__global__ __launch_bounds__(256, 8) void knn_kernel(const float* __restrict__ coords,
                                                     int* __restrict__ knn) {
  __shared__ unsigned long long buf[4][QPW][64];   // per-wave filter buffers
  __shared__ int cnt[4][QPW];
  const int t = threadIdx.x;
  const int w = t >> 6, lane = t & 63;
  const int qbase = blockIdx.x * (4 * QPW) + w * QPW;
  const int b = qbase >> 12;
  const float* cb = coords + (size_t)b * NPTS * 3;

  float qx[QPW], qy[QPW], qz[QPW];
  unsigned long long m[QPW];
#pragma unroll
  for (int q = 0; q < QPW; ++q) {
    const int qi = (qbase + q) & (NPTS - 1);
    qx[q] = cb[(size_t)qi * 3];
    qy[q] = cb[(size_t)qi * 3 + 1];
    qz[q] = cb[(size_t)qi * 3 + 2];
    m[q] = INF_KEY;
  }

  // ---- phase 1: per-lane slice minima over the 64-candidate slices ----
#pragma unroll 4
  for (int s = 0; s < 64; ++s) {
    const int j = s * 64 + lane;
    const float px = cb[3 * j], py = cb[3 * j + 1], pz = cb[3 * j + 2];
#pragma unroll
    for (int q = 0; q < QPW; ++q) {
      float dx = __fsub_rn(qx[q], px);
      float dy = __fsub_rn(qy[q], py);
      float dz = __fsub_rn(qz[q], pz);
      float d = __fadd_rn(__fadd_rn(__fmul_rn(dx, dx), __fmul_rn(dy, dy)), __fmul_rn(dz, dz));
      unsigned long long key = ((unsigned long long)__float_as_uint(d) << 32) | (unsigned)j;
      m[q] = key < m[q] ? key : m[q];
    }
  }
  // ---- thresholds: 16th-smallest slice-min key per query (64 distinct keys
  //      from disjoint slices -> count(key <= K16) >= 16 is guaranteed) ----
  unsigned long long K16[QPW];
#pragma unroll
  for (int q = 0; q < QPW; ++q) K16[q] = __shfl(bitonic64(m[q], lane), 15);
  if (lane < QPW) cnt[w][lane] = 0;

  // ---- phase 2: filter-append (same-wave LDS ops are in-order) ----
#pragma unroll 4
  for (int s = 0; s < 64; ++s) {
    const int j = s * 64 + lane;
    const float px = cb[3 * j], py = cb[3 * j + 1], pz = cb[3 * j + 2];
#pragma unroll
    for (int q = 0; q < QPW; ++q) {
      float dx = __fsub_rn(qx[q], px);
      float dy = __fsub_rn(qy[q], py);
      float dz = __fsub_rn(qz[q], pz);
      float d = __fadd_rn(__fadd_rn(__fmul_rn(dx, dx), __fmul_rn(dy, dy)), __fmul_rn(dz, dz));
      unsigned long long key = ((unsigned long long)__float_as_uint(d) << 32) | (unsigned)j;
      if (key <= K16[q]) {
        int slot = atomicAdd(&cnt[w][q], 1);
        if (slot < 64) buf[w][q][slot] = key;
      }
    }
  }
  // ---- phase 3: exact sort of each filtered set ----
#pragma unroll
  for (int q = 0; q < QPW; ++q) {
    const int n = cnt[w][q];
    unsigned long long v = (lane < n) ? buf[w][q][lane] : INF_KEY;
    v = bitonic64(v, lane);
    if (lane < 16) knn[(size_t)(qbase + q) * 16 + lane] = (int)(v & 0xFFFFFFFFu);
  }
}

// ---------------------------------------------------------------------------
// Kernel 2: x = feat@w1+b1; q=x@wq; k=x@wk; v=x@wv (wave-per-row, readlane).
// ---------------------------------------------------------------------------
#define FT_RPT 8
__global__ __launch_bounds__(256) void ft_kernel(const float* __restrict__ feat,
    const float* __restrict__ w1, const float* __restrict__ b1,
    const float* __restrict__ wq, const float* __restrict__ wk, const float* __restrict__ wv,
    float* __restrict__ qo, float* __restrict__ ko, float* __restrict__ vo) {
  __shared__ float W[4][D * D];
  const int t = threadIdx.x;
  {
    const float4* s0 = (const float4*)w1;
    const float4* s1 = (const float4*)wq;
    const float4* s2 = (const float4*)wk;
    const float4* s3 = (const float4*)wv;
    for (int c = t; c < D * D / 4; c += 256) {
      ((float4*)W[0])[c] = s0[c]; ((float4*)W[1])[c] = s1[c];
      ((float4*)W[2])[c] = s2[c]; ((float4*)W[3])[c] = s3[c];
    }
  }
  __syncthreads();
  const int f = t & 63, w = t >> 6;
  const float b1f = b1[f];
  const int gw = blockIdx.x * 4 + w;
  for (int r = 0; r < FT_RPT; ++r) {
    const int row = gw * FT_RPT + r;
    const float fv = feat[(size_t)row * D + f];
    float x = b1f;
#pragma unroll
    for (int i = 0; i < D; ++i) x = fmaf(rl(fv, i), W[0][i * D + f], x);
    float q = 0.f, kk = 0.f, vv = 0.f;
#pragma unroll
    for (int i = 0; i < D; ++i) {
      float xi = rl(x, i);
      q  = fmaf(xi, W[1][i * D + f], q);
      kk = fmaf(xi, W[2][i * D + f], kk);
      vv = fmaf(xi, W[3][i * D + f], vv);
    }
    qo[(size_t)row * D + f] = q;
    ko[(size_t)row * D + f] = kk;
    vo[(size_t)row * D + f] = vv;
  }
}

// ---------------------------------------------------------------------------
// Kernel 3: MFMA point-transformer core. 4 queries per wave (sequential),
// 16 queries/block -> weight prep amortized 4x. One shared per-wave bf16
// exchange buffer xch for BOTH pe (A-frag build) and a2 (transpose); the
// output-side pe read is register-local (pe_d), so no f32 pe buffer needed.
// w2 is read from global (16KB, L1-resident). LDS 36KB -> 4 blocks/CU.
// ---------------------------------------------------------------------------
__global__ __launch_bounds__(256, 4) void pt_kernel(const float* __restrict__ coords,
    const float* __restrict__ feat,
    const float* __restrict__ qws, const float* __restrict__ kws, const float* __restrict__ vws,
    const int* __restrict__ knn,
    const float* __restrict__ wp1, const float* __restrict__ bp1,
    const float* __restrict__ wp2, const float* __restrict__ bp2,
    const float* __restrict__ wm1, const float* __restrict__ bm1,
    const float* __restrict__ wm2, const float* __restrict__ bm2,
    const float* __restrict__ w2g, const float* __restrict__ b2,
    float* __restrict__ out, float* __restrict__ attn_g) {
  __shared__ short WBp[512 * 8], WBm1[512 * 8], WBm2[512 * 8];  // frag-packed weights
  __shared__ float wp1t[D * 4];       // (wp1_x, wp1_y, wp1_z, bp1) per channel
  __shared__ float biases[4 * D];     // bp2, bm1, bm2, b2
  __shared__ int knnq[4][PT_QPW][16];
  __shared__ short xch[4][16][72];    // per-wave bf16 exchange (pe, then a2); 144B rows (16B-aligned)

  const int t = threadIdx.x;
  // ---- weight prep (frag order: dst[((tt*2+ks)*64 + lane)*8 + j] = W[k][n]) ----
  for (int s = t; s < 512 * 3; s += 256) {
    const int m = s >> 9, rem = s & 511;
    const int tk = rem >> 6, l = rem & 63;
    const int tt = tk >> 1, ks = tk & 1;
    const float* src = (m == 0) ? wp2 : ((m == 1) ? wm1 : wm2);
    short* dst = (m == 0) ? WBp : ((m == 1) ? WBm1 : WBm2);
#pragma unroll
    for (int j = 0; j < 8; ++j) {
      const int k = ((l >> 4) << 3) + j + (ks << 5);
      const int n = (l & 15) + (tt << 4);
      dst[rem * 8 + j] = f2bf(src[k * D + n]);
    }
  }
  if (t < 64) {
    wp1t[t * 4 + 0] = wp1[t];
    wp1t[t * 4 + 1] = wp1[D + t];
    wp1t[t * 4 + 2] = wp1[2 * D + t];
    wp1t[t * 4 + 3] = bp1[t];
    biases[t] = bp2[t]; biases[64 + t] = bm1[t];
    biases[128 + t] = bm2[t]; biases[192 + t] = b2[t];
  }
  const int w = t >> 6, lane = t & 63;
  const int qbase0 = blockIdx.x * (4 * PT_QPW) + w * PT_QPW;
  {
    const int q = lane >> 4, k = lane & 15;
    const int qi = qbase0 + q;
    const int bbase = (qi >> 12) << 12;
    knnq[w][q][k] = bbase + knn[(size_t)qi * 16 + k];
  }
  __syncthreads();

  const int l15 = lane & 15, g = lane >> 4;
  float ovq[PT_QPW];
  float attst[PT_QPW][4][4];  // attn weights (kept for the global store, done in-loop)

  for (int q = 0; q < PT_QPW; ++q) {
    const int qi = qbase0 + q;
    const int gjA = knnq[w][q][l15];
    // ---- h1 = relu(rel @ wp1 + bp1), built directly in A-frag layout ----
    const float qx = coords[(size_t)qi * 3], qy = coords[(size_t)qi * 3 + 1], qz = coords[(size_t)qi * 3 + 2];
    const float rx = qx - coords[(size_t)gjA * 3];
    const float ry = qy - coords[(size_t)gjA * 3 + 1];
    const float rz = qz - coords[(size_t)gjA * 3 + 2];
    short8 ha[2];
#pragma unroll
    for (int ks = 0; ks < 2; ++ks) {
#pragma unroll
      for (int j = 0; j < 8; ++j) {
        const int c = g * 8 + j + ks * 32;
        const float4 wv = *(const float4*)&wp1t[c * 4];
        float h = fmaf(rx, wv.x, fmaf(ry, wv.y, fmaf(rz, wv.z, wv.w)));
        ha[ks][j] = f2bf(fmaxf(h, 0.f));
      }
    }
    // ---- pos_enc = h1 @ wp2 + bp2 (f32 in pe_d regs; bf16 copy to xch) ----
    f32x4 pe_d[4];
#pragma unroll
    for (int tt = 0; tt < 4; ++tt) {
      f32x4 acc = {0.f, 0.f, 0.f, 0.f};
      acc = MFMA16(ha[0], *(const short8*)&WBp[((tt * 2 + 0) * 64 + lane) * 8], acc);
      acc = MFMA16(ha[1], *(const short8*)&WBp[((tt * 2 + 1) * 64 + lane) * 8], acc);
      const float bb = biases[l15 + tt * 16];
#pragma unroll
      for (int r = 0; r < 4; ++r) {
        pe_d[tt][r] = acc[r] + bb;
        xch[w][4 * g + r][l15 + 16 * tt] = f2bf(pe_d[tt][r]);
      }
    }
    __syncthreads();  // xch(pe) visible before cross-lane A-frag build
    // ---- a = q - k_g + pos_enc, in A-frag layout ----
    short8 aa[2];
#pragma unroll
    for (int ks = 0; ks < 2; ++ks) {
      const int c0 = g * 8 + ks * 32;
      const float4 q0 = *(const float4*)&qws[(size_t)qi * D + c0];
      const float4 q1 = *(const float4*)&qws[(size_t)qi * D + c0 + 4];
      const float4 k0 = *(const float4*)&kws[(size_t)gjA * D + c0];
      const float4 k1 = *(const float4*)&kws[(size_t)gjA * D + c0 + 4];
      const short8 pv = *(const short8*)&xch[w][l15][c0];
      aa[ks][0] = f2bf(q0.x - k0.x + bf2f(pv[0]));
      aa[ks][1] = f2bf(q0.y - k0.y + bf2f(pv[1]));
      aa[ks][2] = f2bf(q0.z - k0.z + bf2f(pv[2]));
      aa[ks][3] = f2bf(q0.w - k0.w + bf2f(pv[3]));
      aa[ks][4] = f2bf(q1.x - k1.x + bf2f(pv[4]));
      aa[ks][5] = f2bf(q1.y - k1.y + bf2f(pv[5]));
      aa[ks][6] = f2bf(q1.z - k1.z + bf2f(pv[6]));
      aa[ks][7] = f2bf(q1.w - k1.w + bf2f(pv[7]));
    }
    // ---- a2 = relu(a @ wm1 + bm1) -> bf16 -> xch (reuse; pe dead now) ----
#pragma unroll
    for (int tt = 0; tt < 4; ++tt) {
      f32x4 acc = {0.f, 0.f, 0.f, 0.f};
      acc = MFMA16(aa[0], *(const short8*)&WBm1[((tt * 2 + 0) * 64 + lane) * 8], acc);
      acc = MFMA16(aa[1], *(const short8*)&WBm1[((tt * 2 + 1) * 64 + lane) * 8], acc);
      const float bb = biases[64 + l15 + tt * 16];
#pragma unroll
      for (int r = 0; r < 4; ++r)
        xch[w][4 * g + r][l15 + 16 * tt] = f2bf(fmaxf(acc[r] + bb, 0.f));
    }
    __syncthreads();  // xch(a2) visible before cross-lane reads
    // ---- a3 = a2 @ wm2 + bm2 ----
    const short8 a20 = *(const short8*)&xch[w][l15][g * 8];
    const short8 a21 = *(const short8*)&xch[w][l15][g * 8 + 32];
    f32x4 s3[4];
#pragma unroll
    for (int tt = 0; tt < 4; ++tt) {
      f32x4 acc = {0.f, 0.f, 0.f, 0.f};
      acc = MFMA16(a20, *(const short8*)&WBm2[((tt * 2 + 0) * 64 + lane) * 8], acc);
      acc = MFMA16(a21, *(const short8*)&WBm2[((tt * 2 + 1) * 64 + lane) * 8], acc);
      const float bb = biases[128 + l15 + tt * 16];
#pragma unroll
      for (int r = 0; r < 4; ++r) s3[tt][r] = acc[r] + bb;
    }
    // ---- softmax over the 16 neighbors (rows), per channel (col) ----
#pragma unroll
    for (int tt = 0; tt < 4; ++tt) {
      float v0 = s3[tt][0] * 0.125f, v1 = s3[tt][1] * 0.125f;
      float v2 = s3[tt][2] * 0.125f, v3 = s3[tt][3] * 0.125f;
      float mx = fmaxf(fmaxf(v0, v1), fmaxf(v2, v3));
      mx = fmaxf(mx, __shfl_xor(mx, 16));
      mx = fmaxf(mx, __shfl_xor(mx, 32));
      float e0 = __expf(v0 - mx), e1 = __expf(v1 - mx), e2 = __expf(v2 - mx), e3 = __expf(v3 - mx);
      float sm = (e0 + e1) + (e2 + e3);
      sm += __shfl_xor(sm, 16);
      sm += __shfl_xor(sm, 32);
      const float inv = 1.0f / sm;
      attst[q][tt][0] = e0 * inv; attst[q][tt][1] = e1 * inv;
      attst[q][tt][2] = e2 * inv; attst[q][tt][3] = e3 * inv;
    }
    // ---- store attn output ----
    float* aq = attn_g + (size_t)qi * KNBR * D;
#pragma unroll
    for (int tt = 0; tt < 4; ++tt)
#pragma unroll
      for (int r = 0; r < 4; ++r)
        aq[(4 * g + r) * D + l15 + 16 * tt] = attst[q][tt][r];
    // ---- out_vec = sum_k attn * (v_g + pos_enc); pe is register-local ----
    float ovp[4] = {0.f, 0.f, 0.f, 0.f};
#pragma unroll
    for (int r = 0; r < 4; ++r) {
      const int gjr = knnq[w][q][4 * g + r];
#pragma unroll
      for (int tt = 0; tt < 4; ++tt) {
        const float vv = vws[(size_t)gjr * D + l15 + 16 * tt];
        ovp[tt] = fmaf(attst[q][tt][r], vv + pe_d[tt][r], ovp[tt]);
      }
    }
#pragma unroll
    for (int tt = 0; tt < 4; ++tt) {
      ovp[tt] += __shfl_xor(ovp[tt], 16);
      ovp[tt] += __shfl_xor(ovp[tt], 32);
    }
    ovq[q] = (g == 0) ? ovp[0] : ((g == 1) ? ovp[1] : ((g == 2) ? ovp[2] : ovp[3]));
  }

  // ---- out = ov @ w2 + b2 + feat, 4 queries interleaved (ILP), w2 from L1 ----
  float o2[PT_QPW];
#pragma unroll
  for (int q = 0; q < PT_QPW; ++q) o2[q] = biases[192 + lane];
#pragma unroll 8
  for (int i = 0; i < D; ++i) {
    const float wv = w2g[i * D + lane];
#pragma unroll
    for (int q = 0; q < PT_QPW; ++q) o2[q] = fmaf(rl(ovq[q], i), wv, o2[q]);
  }
#pragma unroll
  for (int q = 0; q < PT_QPW; ++q) {
    const int qi = qbase0 + q;
    out[(size_t)qi * D + lane] = o2[q] + feat[(size_t)qi * D + lane];
  }
}

// ---------------------------------------------------------------------------
extern "C" void kernel_launch(void* const* d_in, const int* in_sizes, int n_in,
                              void* d_out, int out_size, void* d_ws, size_t ws_size,
                              hipStream_t stream) {
  const float* coords = (const float*)d_in[0];
  const float* feat   = (const float*)d_in[1];
  const float* w1  = (const float*)d_in[2];
  const float* b1  = (const float*)d_in[3];
  const float* w2  = (const float*)d_in[4];
  const float* b2  = (const float*)d_in[5];
  const float* wq  = (const float*)d_in[6];
  const float* wk  = (const float*)d_in[7];
  const float* wv  = (const float*)d_in[8];
  const float* wm1 = (const float*)d_in[9];
  const float* bm1 = (const float*)d_in[10];
  const float* wm2 = (const float*)d_in[11];
  const float* bm2 = (const float*)d_in[12];
  const float* wp1 = (const float*)d_in[13];
  const float* bp1 = (const float*)d_in[14];
  const float* wp2 = (const float*)d_in[15];
  const float* bp2 = (const float*)d_in[16];

  // ws layout (disjoint): knn@0 (1MB), qws@1MB, kws@5MB, vws@9MB..13MB.
  int* knn = (int*)d_ws;
  float* qws = (float*)((char*)d_ws + (size_t)1 * (1 << 20));
  float* kws = (float*)((char*)d_ws + (size_t)5 * (1 << 20));
  float* vws = (float*)((char*)d_ws + (size_t)9 * (1 << 20));
  float* out  = (float*)d_out;
  float* attn = out + (size_t)NQ * D;

  hipLaunchKernelGGL(knn_kernel, dim3(NQ / (4 * QPW)), dim3(256), 0, stream,
                     coords, knn);
  hipLaunchKernelGGL(ft_kernel, dim3(NQ / (4 * FT_RPT)), dim3(256), 0, stream,
                     feat, w1, b1, wq, wk, wv, qws, kws, vws);
  hipLaunchKernelGGL(pt_kernel, dim3(NQ / (4 * PT_QPW)), dim3(256), 0, stream,
                     coords, feat, qws, kws, vws, knn,
                     wp1, bp1, wp2, bp2, wm1, bm1, wm2, bm2, w2, b2, out, attn);
}

// Round 10
// 137.142 us; speedup vs baseline: 9.3152x; 1.0012x over previous
//
#include <hip/hip_runtime.h>
#include <hip/hip_bf16.h>

#define BATCH 4
#define NPTS 4096
#define KNBR 16
#define D 64
#define NQ (BATCH * NPTS)
#define QPW 4
#define PT_QPW 4

using short8 = __attribute__((ext_vector_type(8))) short;
using f32x4 = __attribute__((ext_vector_type(4))) float;

__device__ __forceinline__ float rl(float v, int i) {
  return __int_as_float(__builtin_amdgcn_readlane(__float_as_int(v), i));
}
__device__ __forceinline__ short f2bf(float x) {
  __hip_bfloat16 h = __float2bfloat16(x);
  return *reinterpret_cast<short*>(&h);
}
__device__ __forceinline__ float bf2f(short s) {
  union { unsigned u; float f; } v;
  v.u = ((unsigned)(unsigned short)s) << 16;
  return v.f;
}
#define MFMA16(a, b, c) __builtin_amdgcn_mfma_f32_16x16x32_bf16(a, b, c, 0, 0, 0)

#define INF_KEY 0x7F800000FFFFFFFFull

// 64-lane bitonic full sort (ascending by lane) of u64 keys.
__device__ __forceinline__ unsigned long long bitonic64(unsigned long long v, int lane) {
#pragma unroll
  for (int k = 2; k <= 64; k <<= 1) {
#pragma unroll
    for (int j = k >> 1; j > 0; j >>= 1) {
      unsigned long long o = __shfl_xor(v, j);
      const bool up = (lane & k) == 0;
      const bool lower = (lane & j) == 0;
      unsigned long long mn = v < o ? v : o;
      unsigned long long mx = v < o ? o : v;
      v = (up == lower) ? mn : mx;
    }
  }
  return v;
}

// ---------------------------------------------------------------------------
// Kernel 1: exact KNN, 4 queries/wave, candidates read directly from global
// (coords stream is L2-resident: 48KB/batch). No staging, no barriers.
// Same slice partition (j = s*64+lane) and __f*_rn arithmetic as the proven
// round-4/5 kernel -> identical keys, identical K16 threshold semantics.
// ---------------------------------------------------------------------------
__global__ __launch_bounds__(256, 8) void knn_kernel(const float* __restrict__ coords,
                                                     int* __restrict__ knn) {
  __shared__ unsigned long long buf[4][QPW][64];   // per-wave filter buffers
  __shared__ int cnt[4][QPW];
  const int t = threadIdx.x;
  const int w = t >> 6, lane = t & 63;
  const int qbase = blockIdx.x * (4 * QPW) + w * QPW;
  const int b = qbase >> 12;
  const float* cb = coords + (size_t)b * NPTS * 3;

  float qx[QPW], qy[QPW], qz[QPW];
  unsigned long long m[QPW];
#pragma unroll
  for (int q = 0; q < QPW; ++q) {
    const int qi = (qbase + q) & (NPTS - 1);
    qx[q] = cb[(size_t)qi * 3];
    qy[q] = cb[(size_t)qi * 3 + 1];
    qz[q] = cb[(size_t)qi * 3 + 2];
    m[q] = INF_KEY;
  }

  // ---- phase 1: per-lane slice minima over the 64-candidate slices ----
#pragma unroll 4
  for (int s = 0; s < 64; ++s) {
    const int j = s * 64 + lane;
    const float px = cb[3 * j], py = cb[3 * j + 1], pz = cb[3 * j + 2];
#pragma unroll
    for (int q = 0; q < QPW; ++q) {
      float dx = __fsub_rn(qx[q], px);
      float dy = __fsub_rn(qy[q], py);
      float dz = __fsub_rn(qz[q], pz);
      float d = __fadd_rn(__fadd_rn(__fmul_rn(dx, dx), __fmul_rn(dy, dy)), __fmul_rn(dz, dz));
      unsigned long long key = ((unsigned long long)__float_as_uint(d) << 32) | (unsigned)j;
      m[q] = key < m[q] ? key : m[q];
    }
  }
  // ---- thresholds: 16th-smallest slice-min key per query (64 distinct keys
  //      from disjoint slices -> count(key <= K16) >= 16 is guaranteed) ----
  unsigned long long K16[QPW];
#pragma unroll
  for (int q = 0; q < QPW; ++q) K16[q] = __shfl(bitonic64(m[q], lane), 15);
  if (lane < QPW) cnt[w][lane] = 0;

  // ---- phase 2: filter-append (same-wave LDS ops are in-order) ----
#pragma unroll 4
  for (int s = 0; s < 64; ++s) {
    const int j = s * 64 + lane;
    const float px = cb[3 * j], py = cb[3 * j + 1], pz = cb[3 * j + 2];
#pragma unroll
    for (int q = 0; q < QPW; ++q) {
      float dx = __fsub_rn(qx[q], px);
      float dy = __fsub_rn(qy[q], py);
      float dz = __fsub_rn(qz[q], pz);
      float d = __fadd_rn(__fadd_rn(__fmul_rn(dx, dx), __fmul_rn(dy, dy)), __fmul_rn(dz, dz));
      unsigned long long key = ((unsigned long long)__float_as_uint(d) << 32) | (unsigned)j;
      if (key <= K16[q]) {
        int slot = atomicAdd(&cnt[w][q], 1);
        if (slot < 64) buf[w][q][slot] = key;
      }
    }
  }
  // ---- phase 3: exact sort of each filtered set ----
#pragma unroll
  for (int q = 0; q < QPW; ++q) {
    const int n = cnt[w][q];
    unsigned long long v = (lane < n) ? buf[w][q][lane] : INF_KEY;
    v = bitonic64(v, lane);
    if (lane < 16) knn[(size_t)(qbase + q) * 16 + lane] = (int)(v & 0xFFFFFFFFu);
  }
}

// ---------------------------------------------------------------------------
// Kernel 2: x = feat@w1+b1; q=x@wq; k=x@wk; v=x@wv (wave-per-row, readlane).
// ---------------------------------------------------------------------------
#define FT_RPT 8
__global__ __launch_bounds__(256) void ft_kernel(const float* __restrict__ feat,
    const float* __restrict__ w1, const float* __restrict__ b1,
    const float* __restrict__ wq, const float* __restrict__ wk, const float* __restrict__ wv,
    float* __restrict__ qo, float* __restrict__ ko, float* __restrict__ vo) {
  __shared__ float W[4][D * D];
  const int t = threadIdx.x;
  {
    const float4* s0 = (const float4*)w1;
    const float4* s1 = (const float4*)wq;
    const float4* s2 = (const float4*)wk;
    const float4* s3 = (const float4*)wv;
    for (int c = t; c < D * D / 4; c += 256) {
      ((float4*)W[0])[c] = s0[c]; ((float4*)W[1])[c] = s1[c];
      ((float4*)W[2])[c] = s2[c]; ((float4*)W[3])[c] = s3[c];
    }
  }
  __syncthreads();
  const int f = t & 63, w = t >> 6;
  const float b1f = b1[f];
  const int gw = blockIdx.x * 4 + w;
  for (int r = 0; r < FT_RPT; ++r) {
    const int row = gw * FT_RPT + r;
    const float fv = feat[(size_t)row * D + f];
    float x = b1f;
#pragma unroll
    for (int i = 0; i < D; ++i) x = fmaf(rl(fv, i), W[0][i * D + f], x);
    float q = 0.f, kk = 0.f, vv = 0.f;
#pragma unroll
    for (int i = 0; i < D; ++i) {
      float xi = rl(x, i);
      q  = fmaf(xi, W[1][i * D + f], q);
      kk = fmaf(xi, W[2][i * D + f], kk);
      vv = fmaf(xi, W[3][i * D + f], vv);
    }
    qo[(size_t)row * D + f] = q;
    ko[(size_t)row * D + f] = kk;
    vo[(size_t)row * D + f] = vv;
  }
}

// ---------------------------------------------------------------------------
// Kernel 3: MFMA point-transformer core. 4 queries per wave (sequential),
// 16 queries/block -> weight prep amortized 4x. One shared per-wave bf16
// exchange buffer xch for BOTH pe (A-frag build) and a2 (transpose); the
// output-side pe read is register-local (pe_d), so no f32 pe buffer needed.
// w2 is read from global (16KB, L1-resident). LDS 36KB -> 4 blocks/CU.
// ---------------------------------------------------------------------------
__global__ __launch_bounds__(256, 4) void pt_kernel(const float* __restrict__ coords,
    const float* __restrict__ feat,
    const float* __restrict__ qws, const float* __restrict__ kws, const float* __restrict__ vws,
    const int* __restrict__ knn,
    const float* __restrict__ wp1, const float* __restrict__ bp1,
    const float* __restrict__ wp2, const float* __restrict__ bp2,
    const float* __restrict__ wm1, const float* __restrict__ bm1,
    const float* __restrict__ wm2, const float* __restrict__ bm2,
    const float* __restrict__ w2g, const float* __restrict__ b2,
    float* __restrict__ out, float* __restrict__ attn_g) {
  __shared__ short WBp[512 * 8], WBm1[512 * 8], WBm2[512 * 8];  // frag-packed weights
  __shared__ float wp1t[D * 4];       // (wp1_x, wp1_y, wp1_z, bp1) per channel
  __shared__ float biases[4 * D];     // bp2, bm1, bm2, b2
  __shared__ int knnq[4][PT_QPW][16];
  __shared__ short xch[4][16][72];    // per-wave bf16 exchange (pe, then a2); 144B rows (16B-aligned)

  const int t = threadIdx.x;
  // ---- weight prep (frag order: dst[((tt*2+ks)*64 + lane)*8 + j] = W[k][n]) ----
  for (int s = t; s < 512 * 3; s += 256) {
    const int m = s >> 9, rem = s & 511;
    const int tk = rem >> 6, l = rem & 63;
    const int tt = tk >> 1, ks = tk & 1;
    const float* src = (m == 0) ? wp2 : ((m == 1) ? wm1 : wm2);
    short* dst = (m == 0) ? WBp : ((m == 1) ? WBm1 : WBm2);
#pragma unroll
    for (int j = 0; j < 8; ++j) {
      const int k = ((l >> 4) << 3) + j + (ks << 5);
      const int n = (l & 15) + (tt << 4);
      dst[rem * 8 + j] = f2bf(src[k * D + n]);
    }
  }
  if (t < 64) {
    wp1t[t * 4 + 0] = wp1[t];
    wp1t[t * 4 + 1] = wp1[D + t];
    wp1t[t * 4 + 2] = wp1[2 * D + t];
    wp1t[t * 4 + 3] = bp1[t];
    biases[t] = bp2[t]; biases[64 + t] = bm1[t];
    biases[128 + t] = bm2[t]; biases[192 + t] = b2[t];
  }
  const int w = t >> 6, lane = t & 63;
  const int qbase0 = blockIdx.x * (4 * PT_QPW) + w * PT_QPW;
  {
    const int q = lane >> 4, k = lane & 15;
    const int qi = qbase0 + q;
    const int bbase = (qi >> 12) << 12;
    knnq[w][q][k] = bbase + knn[(size_t)qi * 16 + k];
  }
  __syncthreads();

  const int l15 = lane & 15, g = lane >> 4;
  float ovq[PT_QPW];
  float attst[PT_QPW][4][4];  // attn weights (kept for the global store, done in-loop)

  for (int q = 0; q < PT_QPW; ++q) {
    const int qi = qbase0 + q;
    const int gjA = knnq[w][q][l15];
    // ---- h1 = relu(rel @ wp1 + bp1), built directly in A-frag layout ----
    const float qx = coords[(size_t)qi * 3], qy = coords[(size_t)qi * 3 + 1], qz = coords[(size_t)qi * 3 + 2];
    const float rx = qx - coords[(size_t)gjA * 3];
    const float ry = qy - coords[(size_t)gjA * 3 + 1];
    const float rz = qz - coords[(size_t)gjA * 3 + 2];
    short8 ha[2];
#pragma unroll
    for (int ks = 0; ks < 2; ++ks) {
#pragma unroll
      for (int j = 0; j < 8; ++j) {
        const int c = g * 8 + j + ks * 32;
        const float4 wv = *(const float4*)&wp1t[c * 4];
        float h = fmaf(rx, wv.x, fmaf(ry, wv.y, fmaf(rz, wv.z, wv.w)));
        ha[ks][j] = f2bf(fmaxf(h, 0.f));
      }
    }
    // ---- pos_enc = h1 @ wp2 + bp2 (f32 in pe_d regs; bf16 copy to xch) ----
    f32x4 pe_d[4];
#pragma unroll
    for (int tt = 0; tt < 4; ++tt) {
      f32x4 acc = {0.f, 0.f, 0.f, 0.f};
      acc = MFMA16(ha[0], *(const short8*)&WBp[((tt * 2 + 0) * 64 + lane) * 8], acc);
      acc = MFMA16(ha[1], *(const short8*)&WBp[((tt * 2 + 1) * 64 + lane) * 8], acc);
      const float bb = biases[l15 + tt * 16];
#pragma unroll
      for (int r = 0; r < 4; ++r) {
        pe_d[tt][r] = acc[r] + bb;
        xch[w][4 * g + r][l15 + 16 * tt] = f2bf(pe_d[tt][r]);
      }
    }
    __syncthreads();  // xch(pe) visible before cross-lane A-frag build
    // ---- a = q - k_g + pos_enc, in A-frag layout ----
    short8 aa[2];
#pragma unroll
    for (int ks = 0; ks < 2; ++ks) {
      const int c0 = g * 8 + ks * 32;
      const float4 q0 = *(const float4*)&qws[(size_t)qi * D + c0];
      const float4 q1 = *(const float4*)&qws[(size_t)qi * D + c0 + 4];
      const float4 k0 = *(const float4*)&kws[(size_t)gjA * D + c0];
      const float4 k1 = *(const float4*)&kws[(size_t)gjA * D + c0 + 4];
      const short8 pv = *(const short8*)&xch[w][l15][c0];
      aa[ks][0] = f2bf(q0.x - k0.x + bf2f(pv[0]));
      aa[ks][1] = f2bf(q0.y - k0.y + bf2f(pv[1]));
      aa[ks][2] = f2bf(q0.z - k0.z + bf2f(pv[2]));
      aa[ks][3] = f2bf(q0.w - k0.w + bf2f(pv[3]));
      aa[ks][4] = f2bf(q1.x - k1.x + bf2f(pv[4]));
      aa[ks][5] = f2bf(q1.y - k1.y + bf2f(pv[5]));
      aa[ks][6] = f2bf(q1.z - k1.z + bf2f(pv[6]));
      aa[ks][7] = f2bf(q1.w - k1.w + bf2f(pv[7]));
    }
    // ---- a2 = relu(a @ wm1 + bm1) -> bf16 -> xch (reuse; pe dead now) ----
#pragma unroll
    for (int tt = 0; tt < 4; ++tt) {
      f32x4 acc = {0.f, 0.f, 0.f, 0.f};
      acc = MFMA16(aa[0], *(const short8*)&WBm1[((tt * 2 + 0) * 64 + lane) * 8], acc);
      acc = MFMA16(aa[1], *(const short8*)&WBm1[((tt * 2 + 1) * 64 + lane) * 8], acc);
      const float bb = biases[64 + l15 + tt * 16];
#pragma unroll
      for (int r = 0; r < 4; ++r)
        xch[w][4 * g + r][l15 + 16 * tt] = f2bf(fmaxf(acc[r] + bb, 0.f));
    }
    __syncthreads();  // xch(a2) visible before cross-lane reads
    // ---- a3 = a2 @ wm2 + bm2 ----
    const short8 a20 = *(const short8*)&xch[w][l15][g * 8];
    const short8 a21 = *(const short8*)&xch[w][l15][g * 8 + 32];
    f32x4 s3[4];
#pragma unroll
    for (int tt = 0; tt < 4; ++tt) {
      f32x4 acc = {0.f, 0.f, 0.f, 0.f};
      acc = MFMA16(a20, *(const short8*)&WBm2[((tt * 2 + 0) * 64 + lane) * 8], acc);
      acc = MFMA16(a21, *(const short8*)&WBm2[((tt * 2 + 1) * 64 + lane) * 8], acc);
      const float bb = biases[128 + l15 + tt * 16];
#pragma unroll
      for (int r = 0; r < 4; ++r) s3[tt][r] = acc[r] + bb;
    }
    // ---- softmax over the 16 neighbors (rows), per channel (col) ----
#pragma unroll
    for (int tt = 0; tt < 4; ++tt) {
      float v0 = s3[tt][0] * 0.125f, v1 = s3[tt][1] * 0.125f;
      float v2 = s3[tt][2] * 0.125f, v3 = s3[tt][3] * 0.125f;
      float mx = fmaxf(fmaxf(v0, v1), fmaxf(v2, v3));
      mx = fmaxf(mx, __shfl_xor(mx, 16));
      mx = fmaxf(mx, __shfl_xor(mx, 32));
      float e0 = __expf(v0 - mx), e1 = __expf(v1 - mx), e2 = __expf(v2 - mx), e3 = __expf(v3 - mx);
      float sm = (e0 + e1) + (e2 + e3);
      sm += __shfl_xor(sm, 16);
      sm += __shfl_xor(sm, 32);
      const float inv = 1.0f / sm;
      attst[q][tt][0] = e0 * inv; attst[q][tt][1] = e1 * inv;
      attst[q][tt][2] = e2 * inv; attst[q][tt][3] = e3 * inv;
    }
    // ---- store attn output ----
    float* aq = attn_g + (size_t)qi * KNBR * D;
#pragma unroll
    for (int tt = 0; tt < 4; ++tt)
#pragma unroll
      for (int r = 0; r < 4; ++r)
        aq[(4 * g + r) * D + l15 + 16 * tt] = attst[q][tt][r];
    // ---- out_vec = sum_k attn * (v_g + pos_enc); pe is register-local ----
    float ovp[4] = {0.f, 0.f, 0.f, 0.f};
#pragma unroll
    for (int r = 0; r < 4; ++r) {
      const int gjr = knnq[w][q][4 * g + r];
#pragma unroll
      for (int tt = 0; tt < 4; ++tt) {
        const float vv = vws[(size_t)gjr * D + l15 + 16 * tt];
        ovp[tt] = fmaf(attst[q][tt][r], vv + pe_d[tt][r], ovp[tt]);
      }
    }
#pragma unroll
    for (int tt = 0; tt < 4; ++tt) {
      ovp[tt] += __shfl_xor(ovp[tt], 16);
      ovp[tt] += __shfl_xor(ovp[tt], 32);
    }
    ovq[q] = (g == 0) ? ovp[0] : ((g == 1) ? ovp[1] : ((g == 2) ? ovp[2] : ovp[3]));
  }

  // ---- out = ov @ w2 + b2 + feat, 4 queries interleaved (ILP), w2 from L1 ----
  float o2[PT_QPW];
#pragma unroll
  for (int q = 0; q < PT_QPW; ++q) o2[q] = biases[192 + lane];
#pragma unroll 8
  for (int i = 0; i < D; ++i) {
    const float wv = w2g[i * D + lane];
#pragma unroll
    for (int q = 0; q < PT_QPW; ++q) o2[q] = fmaf(rl(ovq[q], i), wv, o2[q]);
  }
#pragma unroll
  for (int q = 0; q < PT_QPW; ++q) {
    const int qi = qbase0 + q;
    out[(size_t)qi * D + lane] = o2[q] + feat[(size_t)qi * D + lane];
  }
}

// ---------------------------------------------------------------------------
extern "C" void kernel_launch(void* const* d_in, const int* in_sizes, int n_in,
                              void* d_out, int out_size, void* d_ws, size_t ws_size,
                              hipStream_t stream) {
  const float* coords = (const float*)d_in[0];
  const float* feat   = (const float*)d_in[1];
  const float* w1  = (const float*)d_in[2];
  const float* b1  = (const float*)d_in[3];
  const float* w2  = (const float*)d_in[4];
  const float* b2  = (const float*)d_in[5];
  const float* wq  = (const float*)d_in[6];
  const float* wk  = (const float*)d_in[7];
  const float* wv  = (const float*)d_in[8];
  const float* wm1 = (const float*)d_in[9];
  const float* bm1 = (const float*)d_in[10];
  const float* wm2 = (const float*)d_in[11];
  const float* bm2 = (const float*)d_in[12];
  const float* wp1 = (const float*)d_in[13];
  const float* bp1 = (const float*)d_in[14];
  const float* wp2 = (const float*)d_in[15];
  const float* bp2 = (const float*)d_in[16];

  // ws layout (disjoint): knn@0 (1MB), qws@1MB, kws@5MB, vws@9MB..13MB.
  int* knn = (int*)d_ws;
  float* qws = (float*)((char*)d_ws + (size_t)1 * (1 << 20));
  float* kws = (float*)((char*)d_ws + (size_t)5 * (1 << 20));
  float* vws = (float*)((char*)d_ws + (size_t)9 * (1 << 20));
  float* out  = (float*)d_out;
  float* attn = out + (size_t)NQ * D;

  hipLaunchKernelGGL(knn_kernel, dim3(NQ / (4 * QPW)), dim3(256), 0, stream,
                     coords, knn);
  hipLaunchKernelGGL(ft_kernel, dim3(NQ / (4 * FT_RPT)), dim3(256), 0, stream,
                     feat, w1, b1, wq, wk, wv, qws, kws, vws);
  hipLaunchKernelGGL(pt_kernel, dim3(NQ / (4 * PT_QPW)), dim3(256), 0, stream,
                     coords, feat, qws, kws, vws, knn,
                     wp1, bp1, wp2, bp2, wm1, bm1, wm2, bm2, w2, b2, out, attn);
}

// Round 11
// 125.089 us; speedup vs baseline: 10.2128x; 1.0964x over previous
//
#include <hip/hip_runtime.h>
#include <hip/hip_bf16.h>

#define BATCH 4
#define NPTS 4096
#define KNBR 16
#define D 64
#define NQ (BATCH * NPTS)
#define QPW 2
#define PT_QPW 4

using short8 = __attribute__((ext_vector_type(8))) short;
using short4v = __attribute__((ext_vector_type(4))) short;
using f32x4 = __attribute__((ext_vector_type(4))) float;

__device__ __forceinline__ float rl(float v, int i) {
  return __int_as_float(__builtin_amdgcn_readlane(__float_as_int(v), i));
}
__device__ __forceinline__ short f2bf(float x) {
  __hip_bfloat16 h = __float2bfloat16(x);
  return *reinterpret_cast<short*>(&h);
}
__device__ __forceinline__ float bf2f(short s) {
  union { unsigned u; float f; } v;
  v.u = ((unsigned)(unsigned short)s) << 16;
  return v.f;
}
#define MFMA16(a, b, c) __builtin_amdgcn_mfma_f32_16x16x32_bf16(a, b, c, 0, 0, 0)

#define INF_KEY 0x7F800000FFFFFFFFull

// 64-lane bitonic full sort (ascending by lane) of u64 keys.
__device__ __forceinline__ unsigned long long bitonic64(unsigned long long v, int lane) {
#pragma unroll
  for (int k = 2; k <= 64; k <<= 1) {
#pragma unroll
    for (int j = k >> 1; j > 0; j >>= 1) {
      unsigned long long o = __shfl_xor(v, j);
      const bool up = (lane & k) == 0;
      const bool lower = (lane & j) == 0;
      unsigned long long mn = v < o ? v : o;
      unsigned long long mx = v < o ? o : v;
      v = (up == lower) ? mn : mx;
    }
  }
  return v;
}

// ---------------------------------------------------------------------------
// Kernel 1: exact KNN, u64 keys throughout (u32 variant faults — keep u64).
// QPW=2 queries/wave -> grid 2048 blocks = 8 blocks/CU = full wave occupancy.
// Same slice partition (j = s*64+lane) and __f*_rn arithmetic as the proven
// round-4..6/10 kernels -> identical keys, identical K16 threshold semantics.
// ---------------------------------------------------------------------------
__global__ __launch_bounds__(256, 8) void knn_kernel(const float* __restrict__ coords,
                                                     int* __restrict__ knn) {
  __shared__ unsigned long long buf[4][QPW][64];   // per-wave filter buffers
  __shared__ int cnt[4][QPW];
  const int t = threadIdx.x;
  const int w = t >> 6, lane = t & 63;
  const int qbase = blockIdx.x * (4 * QPW) + w * QPW;
  const int b = qbase >> 12;
  const float* cb = coords + (size_t)b * NPTS * 3;

  float qx[QPW], qy[QPW], qz[QPW];
  unsigned long long m[QPW];
#pragma unroll
  for (int q = 0; q < QPW; ++q) {
    const int qi = (qbase + q) & (NPTS - 1);
    qx[q] = cb[(size_t)qi * 3];
    qy[q] = cb[(size_t)qi * 3 + 1];
    qz[q] = cb[(size_t)qi * 3 + 2];
    m[q] = INF_KEY;
  }

  // ---- phase 1: per-lane slice minima over the 64-candidate slices ----
#pragma unroll 4
  for (int s = 0; s < 64; ++s) {
    const int j = s * 64 + lane;
    const float px = cb[3 * j], py = cb[3 * j + 1], pz = cb[3 * j + 2];
#pragma unroll
    for (int q = 0; q < QPW; ++q) {
      float dx = __fsub_rn(qx[q], px);
      float dy = __fsub_rn(qy[q], py);
      float dz = __fsub_rn(qz[q], pz);
      float d = __fadd_rn(__fadd_rn(__fmul_rn(dx, dx), __fmul_rn(dy, dy)), __fmul_rn(dz, dz));
      unsigned long long key = ((unsigned long long)__float_as_uint(d) << 32) | (unsigned)j;
      m[q] = key < m[q] ? key : m[q];
    }
  }
  // ---- thresholds: 16th-smallest slice-min key per query (64 distinct keys
  //      from disjoint slices -> count(key <= K16) >= 16 is guaranteed) ----
  unsigned long long K16[QPW];
#pragma unroll
  for (int q = 0; q < QPW; ++q) K16[q] = __shfl(bitonic64(m[q], lane), 15);
  if (lane < QPW) cnt[w][lane] = 0;

  // ---- phase 2: filter-append (same-wave LDS ops are in-order) ----
#pragma unroll 4
  for (int s = 0; s < 64; ++s) {
    const int j = s * 64 + lane;
    const float px = cb[3 * j], py = cb[3 * j + 1], pz = cb[3 * j + 2];
#pragma unroll
    for (int q = 0; q < QPW; ++q) {
      float dx = __fsub_rn(qx[q], px);
      float dy = __fsub_rn(qy[q], py);
      float dz = __fsub_rn(qz[q], pz);
      float d = __fadd_rn(__fadd_rn(__fmul_rn(dx, dx), __fmul_rn(dy, dy)), __fmul_rn(dz, dz));
      unsigned long long key = ((unsigned long long)__float_as_uint(d) << 32) | (unsigned)j;
      if (key <= K16[q]) {
        int slot = atomicAdd(&cnt[w][q], 1);
        if (slot < 64) buf[w][q][slot] = key;
      }
    }
  }
  // ---- phase 3: exact sort of each filtered set ----
#pragma unroll
  for (int q = 0; q < QPW; ++q) {
    const int n = cnt[w][q];
    unsigned long long v = (lane < n) ? buf[w][q][lane] : INF_KEY;
    v = bitonic64(v, lane);
    if (lane < 16) knn[(size_t)(qbase + q) * 16 + lane] = (int)(v & 0xFFFFFFFFu);
  }
}

// ---------------------------------------------------------------------------
// Kernel 2: x = feat@w1+b1; q=x@wq; k=x@wk; v=x@wv (wave-per-row, readlane).
// ---------------------------------------------------------------------------
#define FT_RPT 8
__global__ __launch_bounds__(256) void ft_kernel(const float* __restrict__ feat,
    const float* __restrict__ w1, const float* __restrict__ b1,
    const float* __restrict__ wq, const float* __restrict__ wk, const float* __restrict__ wv,
    float* __restrict__ qo, float* __restrict__ ko, float* __restrict__ vo) {
  __shared__ float W[4][D * D];
  const int t = threadIdx.x;
  {
    const float4* s0 = (const float4*)w1;
    const float4* s1 = (const float4*)wq;
    const float4* s2 = (const float4*)wk;
    const float4* s3 = (const float4*)wv;
    for (int c = t; c < D * D / 4; c += 256) {
      ((float4*)W[0])[c] = s0[c]; ((float4*)W[1])[c] = s1[c];
      ((float4*)W[2])[c] = s2[c]; ((float4*)W[3])[c] = s3[c];
    }
  }
  __syncthreads();
  const int f = t & 63, w = t >> 6;
  const float b1f = b1[f];
  const int gw = blockIdx.x * 4 + w;
  for (int r = 0; r < FT_RPT; ++r) {
    const int row = gw * FT_RPT + r;
    const float fv = feat[(size_t)row * D + f];
    float x = b1f;
#pragma unroll
    for (int i = 0; i < D; ++i) x = fmaf(rl(fv, i), W[0][i * D + f], x);
    float q = 0.f, kk = 0.f, vv = 0.f;
#pragma unroll
    for (int i = 0; i < D; ++i) {
      float xi = rl(x, i);
      q  = fmaf(xi, W[1][i * D + f], q);
      kk = fmaf(xi, W[2][i * D + f], kk);
      vv = fmaf(xi, W[3][i * D + f], vv);
    }
    qo[(size_t)row * D + f] = q;
    ko[(size_t)row * D + f] = kk;
    vo[(size_t)row * D + f] = vv;
  }
}

// ---------------------------------------------------------------------------
// Kernel 3: MFMA point-transformer core (round-6 base + coalesced attn store).
// 4 queries per wave; per-wave bf16 exchange buffer xch reused for pe
// (A-frag build), a2 (transpose), and the attn-store transpose (bf16
// rounding <=0.4% rel << 0.101 threshold). attn stores: 4x 1KB float4 waves.
// ---------------------------------------------------------------------------
__global__ __launch_bounds__(256, 4) void pt_kernel(const float* __restrict__ coords,
    const float* __restrict__ feat,
    const float* __restrict__ qws, const float* __restrict__ kws, const float* __restrict__ vws,
    const int* __restrict__ knn,
    const float* __restrict__ wp1, const float* __restrict__ bp1,
    const float* __restrict__ wp2, const float* __restrict__ bp2,
    const float* __restrict__ wm1, const float* __restrict__ bm1,
    const float* __restrict__ wm2, const float* __restrict__ bm2,
    const float* __restrict__ w2g, const float* __restrict__ b2,
    float* __restrict__ out, float* __restrict__ attn_g) {
  __shared__ short WBp[512 * 8], WBm1[512 * 8], WBm2[512 * 8];  // frag-packed weights
  __shared__ float wp1t[D * 4];       // (wp1_x, wp1_y, wp1_z, bp1) per channel
  __shared__ float biases[4 * D];     // bp2, bm1, bm2, b2
  __shared__ int knnq[4][PT_QPW][16];
  __shared__ short xch[4][16][72];    // per-wave bf16 exchange; 144B rows (16B-aligned)

  const int t = threadIdx.x;
  // ---- weight prep (frag order: dst[((tt*2+ks)*64 + lane)*8 + j] = W[k][n]) ----
  for (int s = t; s < 512 * 3; s += 256) {
    const int m = s >> 9, rem = s & 511;
    const int tk = rem >> 6, l = rem & 63;
    const int tt = tk >> 1, ks = tk & 1;
    const float* src = (m == 0) ? wp2 : ((m == 1) ? wm1 : wm2);
    short* dst = (m == 0) ? WBp : ((m == 1) ? WBm1 : WBm2);
#pragma unroll
    for (int j = 0; j < 8; ++j) {
      const int k = ((l >> 4) << 3) + j + (ks << 5);
      const int n = (l & 15) + (tt << 4);
      dst[rem * 8 + j] = f2bf(src[k * D + n]);
    }
  }
  if (t < 64) {
    wp1t[t * 4 + 0] = wp1[t];
    wp1t[t * 4 + 1] = wp1[D + t];
    wp1t[t * 4 + 2] = wp1[2 * D + t];
    wp1t[t * 4 + 3] = bp1[t];
    biases[t] = bp2[t]; biases[64 + t] = bm1[t];
    biases[128 + t] = bm2[t]; biases[192 + t] = b2[t];
  }
  const int w = t >> 6, lane = t & 63;
  const int qbase0 = blockIdx.x * (4 * PT_QPW) + w * PT_QPW;
  {
    const int q = lane >> 4, k = lane & 15;
    const int qi = qbase0 + q;
    const int bbase = (qi >> 12) << 12;
    knnq[w][q][k] = bbase + knn[(size_t)qi * 16 + k];
  }
  __syncthreads();

  const int l15 = lane & 15, g = lane >> 4;
  float ovq[PT_QPW];

  for (int q = 0; q < PT_QPW; ++q) {
    const int qi = qbase0 + q;
    const int gjA = knnq[w][q][l15];
    // ---- h1 = relu(rel @ wp1 + bp1), built directly in A-frag layout ----
    const float qx = coords[(size_t)qi * 3], qy = coords[(size_t)qi * 3 + 1], qz = coords[(size_t)qi * 3 + 2];
    const float rx = qx - coords[(size_t)gjA * 3];
    const float ry = qy - coords[(size_t)gjA * 3 + 1];
    const float rz = qz - coords[(size_t)gjA * 3 + 2];
    short8 ha[2];
#pragma unroll
    for (int ks = 0; ks < 2; ++ks) {
#pragma unroll
      for (int j = 0; j < 8; ++j) {
        const int c = g * 8 + j + ks * 32;
        const float4 wv = *(const float4*)&wp1t[c * 4];
        float h = fmaf(rx, wv.x, fmaf(ry, wv.y, fmaf(rz, wv.z, wv.w)));
        ha[ks][j] = f2bf(fmaxf(h, 0.f));
      }
    }
    // ---- pos_enc = h1 @ wp2 + bp2 (f32 in pe_d regs; bf16 copy to xch) ----
    f32x4 pe_d[4];
#pragma unroll
    for (int tt = 0; tt < 4; ++tt) {
      f32x4 acc = {0.f, 0.f, 0.f, 0.f};
      acc = MFMA16(ha[0], *(const short8*)&WBp[((tt * 2 + 0) * 64 + lane) * 8], acc);
      acc = MFMA16(ha[1], *(const short8*)&WBp[((tt * 2 + 1) * 64 + lane) * 8], acc);
      const float bb = biases[l15 + tt * 16];
#pragma unroll
      for (int r = 0; r < 4; ++r) {
        pe_d[tt][r] = acc[r] + bb;
        xch[w][4 * g + r][l15 + 16 * tt] = f2bf(pe_d[tt][r]);
      }
    }
    __syncthreads();  // xch(pe) visible before cross-lane A-frag build
    // ---- a = q - k_g + pos_enc, in A-frag layout ----
    short8 aa[2];
#pragma unroll
    for (int ks = 0; ks < 2; ++ks) {
      const int c0 = g * 8 + ks * 32;
      const float4 q0 = *(const float4*)&qws[(size_t)qi * D + c0];
      const float4 q1 = *(const float4*)&qws[(size_t)qi * D + c0 + 4];
      const float4 k0 = *(const float4*)&kws[(size_t)gjA * D + c0];
      const float4 k1 = *(const float4*)&kws[(size_t)gjA * D + c0 + 4];
      const short8 pv = *(const short8*)&xch[w][l15][c0];
      aa[ks][0] = f2bf(q0.x - k0.x + bf2f(pv[0]));
      aa[ks][1] = f2bf(q0.y - k0.y + bf2f(pv[1]));
      aa[ks][2] = f2bf(q0.z - k0.z + bf2f(pv[2]));
      aa[ks][3] = f2bf(q0.w - k0.w + bf2f(pv[3]));
      aa[ks][4] = f2bf(q1.x - k1.x + bf2f(pv[4]));
      aa[ks][5] = f2bf(q1.y - k1.y + bf2f(pv[5]));
      aa[ks][6] = f2bf(q1.z - k1.z + bf2f(pv[6]));
      aa[ks][7] = f2bf(q1.w - k1.w + bf2f(pv[7]));
    }
    // ---- a2 = relu(a @ wm1 + bm1) -> bf16 -> xch (reuse; pe dead now) ----
#pragma unroll
    for (int tt = 0; tt < 4; ++tt) {
      f32x4 acc = {0.f, 0.f, 0.f, 0.f};
      acc = MFMA16(aa[0], *(const short8*)&WBm1[((tt * 2 + 0) * 64 + lane) * 8], acc);
      acc = MFMA16(aa[1], *(const short8*)&WBm1[((tt * 2 + 1) * 64 + lane) * 8], acc);
      const float bb = biases[64 + l15 + tt * 16];
#pragma unroll
      for (int r = 0; r < 4; ++r)
        xch[w][4 * g + r][l15 + 16 * tt] = f2bf(fmaxf(acc[r] + bb, 0.f));
    }
    __syncthreads();  // xch(a2) visible before cross-lane reads
    // ---- a3 = a2 @ wm2 + bm2 ----
    const short8 a20 = *(const short8*)&xch[w][l15][g * 8];
    const short8 a21 = *(const short8*)&xch[w][l15][g * 8 + 32];
    f32x4 s3[4];
#pragma unroll
    for (int tt = 0; tt < 4; ++tt) {
      f32x4 acc = {0.f, 0.f, 0.f, 0.f};
      acc = MFMA16(a20, *(const short8*)&WBm2[((tt * 2 + 0) * 64 + lane) * 8], acc);
      acc = MFMA16(a21, *(const short8*)&WBm2[((tt * 2 + 1) * 64 + lane) * 8], acc);
      const float bb = biases[128 + l15 + tt * 16];
#pragma unroll
      for (int r = 0; r < 4; ++r) s3[tt][r] = acc[r] + bb;
    }
    // ---- softmax over the 16 neighbors (rows), per channel (col) ----
    float att[4][4];
#pragma unroll
    for (int tt = 0; tt < 4; ++tt) {
      float v0 = s3[tt][0] * 0.125f, v1 = s3[tt][1] * 0.125f;
      float v2 = s3[tt][2] * 0.125f, v3 = s3[tt][3] * 0.125f;
      float mx = fmaxf(fmaxf(v0, v1), fmaxf(v2, v3));
      mx = fmaxf(mx, __shfl_xor(mx, 16));
      mx = fmaxf(mx, __shfl_xor(mx, 32));
      float e0 = __expf(v0 - mx), e1 = __expf(v1 - mx), e2 = __expf(v2 - mx), e3 = __expf(v3 - mx);
      float sm = (e0 + e1) + (e2 + e3);
      sm += __shfl_xor(sm, 16);
      sm += __shfl_xor(sm, 32);
      const float inv = 1.0f / sm;
      att[tt][0] = e0 * inv; att[tt][1] = e1 * inv;
      att[tt][2] = e2 * inv; att[tt][3] = e3 * inv;
    }
    // ---- attn store: bf16 bounce via xch -> 4x 1KB coalesced stores ----
    __syncthreads();  // xch(a2) reads complete in all lanes
#pragma unroll
    for (int tt = 0; tt < 4; ++tt)
#pragma unroll
      for (int r = 0; r < 4; ++r)
        xch[w][4 * g + r][l15 + 16 * tt] = f2bf(att[tt][r]);
    __syncthreads();  // xch(attn) visible
    {
      float* aq = attn_g + (size_t)qi * KNBR * D;
#pragma unroll
      for (int k = 0; k < 4; ++k) {
        const short4v sv = *(const short4v*)&xch[w][g + 4 * k][4 * l15];
        float4 fv;
        fv.x = bf2f(sv.x); fv.y = bf2f(sv.y); fv.z = bf2f(sv.z); fv.w = bf2f(sv.w);
        *(float4*)(aq + lane * 4 + k * 256) = fv;
      }
    }
    // ---- out_vec = sum_k attn * (v_g + pos_enc); pe is register-local ----
    float ovp[4] = {0.f, 0.f, 0.f, 0.f};
#pragma unroll
    for (int r = 0; r < 4; ++r) {
      const int gjr = knnq[w][q][4 * g + r];
#pragma unroll
      for (int tt = 0; tt < 4; ++tt) {
        const float vv = vws[(size_t)gjr * D + l15 + 16 * tt];
        ovp[tt] = fmaf(att[tt][r], vv + pe_d[tt][r], ovp[tt]);
      }
    }
#pragma unroll
    for (int tt = 0; tt < 4; ++tt) {
      ovp[tt] += __shfl_xor(ovp[tt], 16);
      ovp[tt] += __shfl_xor(ovp[tt], 32);
    }
    ovq[q] = (g == 0) ? ovp[0] : ((g == 1) ? ovp[1] : ((g == 2) ? ovp[2] : ovp[3]));
  }

  // ---- out = ov @ w2 + b2 + feat, 4 queries interleaved (ILP), w2 from L1 ----
  float o2[PT_QPW];
#pragma unroll
  for (int q = 0; q < PT_QPW; ++q) o2[q] = biases[192 + lane];
#pragma unroll 8
  for (int i = 0; i < D; ++i) {
    const float wv = w2g[i * D + lane];
#pragma unroll
    for (int q = 0; q < PT_QPW; ++q) o2[q] = fmaf(rl(ovq[q], i), wv, o2[q]);
  }
#pragma unroll
  for (int q = 0; q < PT_QPW; ++q) {
    const int qi = qbase0 + q;
    out[(size_t)qi * D + lane] = o2[q] + feat[(size_t)qi * D + lane];
  }
}

// ---------------------------------------------------------------------------
extern "C" void kernel_launch(void* const* d_in, const int* in_sizes, int n_in,
                              void* d_out, int out_size, void* d_ws, size_t ws_size,
                              hipStream_t stream) {
  const float* coords = (const float*)d_in[0];
  const float* feat   = (const float*)d_in[1];
  const float* w1  = (const float*)d_in[2];
  const float* b1  = (const float*)d_in[3];
  const float* w2  = (const float*)d_in[4];
  const float* b2  = (const float*)d_in[5];
  const float* wq  = (const float*)d_in[6];
  const float* wk  = (const float*)d_in[7];
  const float* wv  = (const float*)d_in[8];
  const float* wm1 = (const float*)d_in[9];
  const float* bm1 = (const float*)d_in[10];
  const float* wm2 = (const float*)d_in[11];
  const float* bm2 = (const float*)d_in[12];
  const float* wp1 = (const float*)d_in[13];
  const float* bp1 = (const float*)d_in[14];
  const float* wp2 = (const float*)d_in[15];
  const float* bp2 = (const float*)d_in[16];

  // ws layout (disjoint): knn@0 (1MB), qws@1MB, kws@5MB, vws@9MB..13MB.
  int* knn = (int*)d_ws;
  float* qws = (float*)((char*)d_ws + (size_t)1 * (1 << 20));
  float* kws = (float*)((char*)d_ws + (size_t)5 * (1 << 20));
  float* vws = (float*)((char*)d_ws + (size_t)9 * (1 << 20));
  float* out  = (float*)d_out;
  float* attn = out + (size_t)NQ * D;

  hipLaunchKernelGGL(knn_kernel, dim3(NQ / (4 * QPW)), dim3(256), 0, stream,
                     coords, knn);
  hipLaunchKernelGGL(ft_kernel, dim3(NQ / (4 * FT_RPT)), dim3(256), 0, stream,
                     feat, w1, b1, wq, wk, wv, qws, kws, vws);
  hipLaunchKernelGGL(pt_kernel, dim3(NQ / (4 * PT_QPW)), dim3(256), 0, stream,
                     coords, feat, qws, kws, vws, knn,
                     wp1, bp1, wp2, bp2, wm1, bm1, wm2, bm2, w2, b2, out, attn);
}